// Round 13
// baseline (464.748 us; speedup 1.0000x reference)
//
#include <hip/hip_runtime.h>

typedef __attribute__((ext_vector_type(8))) short short8v;
typedef __attribute__((ext_vector_type(4))) short short4v;
typedef __attribute__((ext_vector_type(4))) float f32x4;

__device__ __forceinline__ float lrelu(float x) { return x >= 0.f ? x : 0.05f * x; }

__device__ __forceinline__ unsigned short bf16_rne(float x) {
    unsigned u = __float_as_uint(x);
    u += 0x7FFFu + ((u >> 16) & 1u);
    return (unsigned short)(u >> 16);
}
__device__ __forceinline__ float bf16_to_f(unsigned short h) {
    return __uint_as_float(((unsigned)h) << 16);
}
__device__ __forceinline__ void split2(float x, unsigned short& hi, unsigned short& lo) {
    hi = bf16_rne(x);
    lo = bf16_rne(x - bf16_to_f(hi));
}

// ================= MFMA machinery =================
// A-frag (M=16,K=32): lane holds A[row=lane&15][k=(lane>>4)*8+i]
// B-frag: lane holds B[k][frag col16=lane&15]; COLUMN INTERLEAVE: frag t, col16 c -> global col 4c+t.
// C/D: col16=lane&15, row=(lane>>4)*4+reg
// LDS A layout per plane: A[row][k] shorts, 16B slots XOR-swizzled: slot=(k>>3)^(row&7); lo plane at +4096.
// Precision: weights hi/lo; staged fp32 tensors (n, aggr) hi/lo; e/u/v global bf16;
// hidden activations H single bf16. Round-9/10 lesson: no in-thread multi-tile pipelining.
// Round-13: raise launch_bounds occupancy caps (latency-bound kernels, VGPR headroom).

__device__ __forceinline__ void stageW(const float* src, int row0, int nrows,
                                       short* __restrict__ A, int wm, int lane)
{
    #pragma unroll
    for (int it = 0; it < 4; ++it) {
        const int q = it * 64 + lane;
        const int rl = wm * 16 + (q >> 4);
        const int k0 = (q & 15) << 2;
        const int grow = row0 + rl;
        float4 x = (grow < nrows) ? *reinterpret_cast<const float4*>(src + (long long)grow * 64 + k0)
                                  : make_float4(0.f, 0.f, 0.f, 0.f);
        unsigned short h0,h1,h2,h3,l0,l1,l2,l3;
        split2(x.x, h0, l0); split2(x.y, h1, l1); split2(x.z, h2, l2); split2(x.w, h3, l3);
        const int off = rl * 64 + ((((k0 >> 3) ^ (rl & 7))) << 3) + (k0 & 7);
        short4v hv; hv[0]=(short)h0; hv[1]=(short)h1; hv[2]=(short)h2; hv[3]=(short)h3;
        short4v lv; lv[0]=(short)l0; lv[1]=(short)l1; lv[2]=(short)l2; lv[3]=(short)l3;
        *reinterpret_cast<short4v*>(A + off) = hv;
        *reinterpret_cast<short4v*>(A + 4096 + off) = lv;
    }
}

__device__ __forceinline__ void gemm64(const short* __restrict__ A, const short* __restrict__ wf,
                                       int row, int g, int lane, f32x4* __restrict__ acc)
{
    #pragma unroll
    for (int s = 0; s < 2; ++s) {
        const int k8 = s * 4 + g;
        const int aoff = row * 64 + ((k8 ^ (row & 7)) << 3);
        const short8v a_hi = *reinterpret_cast<const short8v*>(A + aoff);
        const short8v a_lo = *reinterpret_cast<const short8v*>(A + 4096 + aoff);
        #pragma unroll
        for (int t = 0; t < 4; ++t) {
            const short8v b_hi = *reinterpret_cast<const short8v*>(wf + ((s*4+t)*2+0)*512 + lane*8);
            const short8v b_lo = *reinterpret_cast<const short8v*>(wf + ((s*4+t)*2+1)*512 + lane*8);
            acc[t] = __builtin_amdgcn_mfma_f32_16x16x32_bf16(a_hi, b_hi, acc[t], 0, 0, 0);
            acc[t] = __builtin_amdgcn_mfma_f32_16x16x32_bf16(a_lo, b_hi, acc[t], 0, 0, 0);
            acc[t] = __builtin_amdgcn_mfma_f32_16x16x32_bf16(a_hi, b_lo, acc[t], 0, 0, 0);
        }
    }
}

__device__ __forceinline__ void gemm64h(const short* __restrict__ A, const short* __restrict__ wf,
                                        int row, int g, int lane, f32x4* __restrict__ acc)
{
    #pragma unroll
    for (int s = 0; s < 2; ++s) {
        const int k8 = s * 4 + g;
        const int aoff = row * 64 + ((k8 ^ (row & 7)) << 3);
        const short8v a = *reinterpret_cast<const short8v*>(A + aoff);
        #pragma unroll
        for (int t = 0; t < 4; ++t) {
            const short8v b_hi = *reinterpret_cast<const short8v*>(wf + ((s*4+t)*2+0)*512 + lane*8);
            const short8v b_lo = *reinterpret_cast<const short8v*>(wf + ((s*4+t)*2+1)*512 + lane*8);
            acc[t] = __builtin_amdgcn_mfma_f32_16x16x32_bf16(a, b_hi, acc[t], 0, 0, 0);
            acc[t] = __builtin_amdgcn_mfma_f32_16x16x32_bf16(a, b_lo, acc[t], 0, 0, 0);
        }
    }
}

__device__ __forceinline__ void repack1(short* __restrict__ A, const float4* __restrict__ q,
                                        int wm, int g, int c4)
{
    #pragma unroll
    for (int r = 0; r < 4; ++r) {
        const int rl = wm * 16 + g * 4 + r;
        const int off = rl * 64 + (((c4 >> 3) ^ (rl & 7)) << 3) + (c4 & 7);
        short4v hv;
        hv[0] = (short)bf16_rne(q[r].x);
        hv[1] = (short)bf16_rne(q[r].y);
        hv[2] = (short)bf16_rne(q[r].z);
        hv[3] = (short)bf16_rne(q[r].w);
        *reinterpret_cast<short4v*>(A + off) = hv;
    }
}

// Preformat 64x64 fp32 W[k][col] chunks -> hi/lo B-fragments (interleaved col map).
__global__ void k_prepw(const float* __restrict__ emW1, const float* __restrict__ emW2,
                        const float* __restrict__ nmW1, const float* __restrict__ nmW2,
                        const float* __restrict__ eeW2, const float* __restrict__ neW2,
                        const float* __restrict__ decW1,
                        short* __restrict__ wf)
{
    const int cid = blockIdx.x;
    const float* src;
    if (cid < 21) {
        const int layer = cid / 7, j = cid % 7;
        src =
            j == 0 ? emW1 + (size_t)layer * 12288 :
            j == 1 ? emW1 + (size_t)layer * 12288 + 4096 :
            j == 2 ? emW1 + (size_t)layer * 12288 + 8192 :
            j == 3 ? emW2 + (size_t)layer * 4096 :
            j == 4 ? nmW1 + (size_t)layer * 8192 :
            j == 5 ? nmW1 + (size_t)layer * 8192 + 4096 :
                     nmW2 + (size_t)layer * 4096;
    } else {
        src = (cid == 21) ? eeW2 : (cid == 22) ? neW2 : decW1;
    }
    short* dst = wf + (size_t)cid * 8192;
    for (int fr = threadIdx.x; fr < 1024; fr += 256) {
        const int lane = fr & 63;
        const int stp = fr >> 6;
        const int p = stp & 1;
        const int st = stp >> 1;
        const int s = st >> 2, t = st & 3;
        const int col = ((lane & 15) << 2) + t;
        const int k0 = s * 32 + (lane >> 4) * 8;
        short8v o;
        #pragma unroll
        for (int i = 0; i < 8; ++i) {
            const float w = src[(k0 + i) * 64 + col];
            const unsigned short hi = bf16_rne(w);
            o[i] = (short)(p ? bf16_rne(w - bf16_to_f(hi)) : hi);
        }
        *reinterpret_cast<short8v*>(dst + fr * 8) = o;
    }
}

// ---------------- encoder; MAKEUV: also emit u,v (bf16); OUTBF16: bf16 output (edge stream) ----------------
template<int DIN, bool PERM, bool MAKEUV, bool OUTBF16>
__global__ __launch_bounds__(256, 6) void k_enc_mf(
    const float* __restrict__ x, const int* __restrict__ csr,
    const float* __restrict__ W1, const float* __restrict__ b1,
    const short* __restrict__ wfW2, const float* __restrict__ b2,
    const float* __restrict__ gam, const float* __restrict__ bet,
    float* __restrict__ out,
    const short* __restrict__ wfB, const short* __restrict__ wfC,
    unsigned short* __restrict__ u, unsigned short* __restrict__ v, int nrows)
{
    __shared__ short Hf[4096];
    const int row0 = blockIdx.x * 64;
    const int lane = threadIdx.x & 63;
    const int wm = threadIdx.x >> 6;
    const int g = lane >> 4, c = lane & 15;
    const int c4 = c << 2;
    const int rowA = wm * 16 + c;

    long long orig[4];
    #pragma unroll
    for (int r = 0; r < 4; ++r) {
        const int grow = row0 + wm * 16 + g * 4 + r;
        orig[r] = (grow < nrows) ? (long long)(PERM ? csr[grow] : grow) : -1;
    }

    const f32x4 z4 = {0.f, 0.f, 0.f, 0.f};
    f32x4 acc[4];
    #pragma unroll
    for (int t = 0; t < 4; ++t) acc[t] = z4;

    #pragma unroll
    for (int kq = 0; kq < DIN / 4; ++kq) {
        float xv[4][4];
        #pragma unroll
        for (int r = 0; r < 4; ++r) {
            float4 t4 = make_float4(0.f, 0.f, 0.f, 0.f);
            if (orig[r] >= 0)
                t4 = *reinterpret_cast<const float4*>(x + orig[r] * DIN + kq * 4);
            xv[r][0] = t4.x; xv[r][1] = t4.y; xv[r][2] = t4.z; xv[r][3] = t4.w;
        }
        #pragma unroll
        for (int i = 0; i < 4; ++i) {
            const int k = kq * 4 + i;
            const float4 w4 = *reinterpret_cast<const float4*>(W1 + k * 64 + c4);
            const float wv[4] = {w4.x, w4.y, w4.z, w4.w};
            #pragma unroll
            for (int t = 0; t < 4; ++t)
                #pragma unroll
                for (int r = 0; r < 4; ++r)
                    acc[t][r] = fmaf(xv[r][i], wv[t], acc[t][r]);
        }
    }

    const float4 b1q = *reinterpret_cast<const float4*>(b1 + c4);
    float4 hq[4];
    #pragma unroll
    for (int r = 0; r < 4; ++r) {
        hq[r].x = lrelu(acc[0][r] + b1q.x);
        hq[r].y = lrelu(acc[1][r] + b1q.y);
        hq[r].z = lrelu(acc[2][r] + b1q.z);
        hq[r].w = lrelu(acc[3][r] + b1q.w);
    }
    repack1(Hf, hq, wm, g, c4);
    __builtin_amdgcn_wave_barrier();

    f32x4 acc2[4];
    #pragma unroll
    for (int t = 0; t < 4; ++t) acc2[t] = z4;
    gemm64h(Hf, wfW2, rowA, g, lane, acc2);

    const float4 b2q = *reinterpret_cast<const float4*>(b2 + c4);
    const float b2a[4] = {b2q.x, b2q.y, b2q.z, b2q.w};
    #pragma unroll
    for (int t = 0; t < 4; ++t) {
        #pragma unroll
        for (int r = 0; r < 4; ++r) acc2[t][r] = lrelu(acc2[t][r] + b2a[t]);
    }
    const float4 gq = *reinterpret_cast<const float4*>(gam + c4);
    const float4 bq = *reinterpret_cast<const float4*>(bet + c4);
    float4 nq[4];
    #pragma unroll
    for (int r = 0; r < 4; ++r) {
        float s = acc2[0][r] + acc2[1][r] + acc2[2][r] + acc2[3][r];
        s += __shfl_xor(s, 1); s += __shfl_xor(s, 2); s += __shfl_xor(s, 4); s += __shfl_xor(s, 8);
        const float mu = s * 0.015625f;
        float q = 0.f;
        #pragma unroll
        for (int t = 0; t < 4; ++t) { const float d = acc2[t][r] - mu; q = fmaf(d, d, q); }
        q += __shfl_xor(q, 1); q += __shfl_xor(q, 2); q += __shfl_xor(q, 4); q += __shfl_xor(q, 8);
        const float rs = rsqrtf(q * 0.015625f + 1e-5f);
        nq[r].x = (acc2[0][r] - mu) * rs * gq.x + bq.x;
        nq[r].y = (acc2[1][r] - mu) * rs * gq.y + bq.y;
        nq[r].z = (acc2[2][r] - mu) * rs * gq.z + bq.z;
        nq[r].w = (acc2[3][r] - mu) * rs * gq.w + bq.w;
        const int grow = row0 + wm * 16 + g * 4 + r;
        if (grow < nrows) {
            if constexpr (OUTBF16) {
                short4v st;
                st[0] = (short)bf16_rne(nq[r].x);
                st[1] = (short)bf16_rne(nq[r].y);
                st[2] = (short)bf16_rne(nq[r].z);
                st[3] = (short)bf16_rne(nq[r].w);
                *reinterpret_cast<short4v*>(reinterpret_cast<unsigned short*>(out) + (long long)grow * 64 + c4) = st;
            } else {
                *reinterpret_cast<float4*>(out + (long long)grow * 64 + c4) = nq[r];
            }
        }
    }

    if constexpr (MAKEUV) {
        __builtin_amdgcn_wave_barrier();
        repack1(Hf, nq, wm, g, c4);
        __builtin_amdgcn_wave_barrier();
        #pragma unroll
        for (int t = 0; t < 4; ++t) acc2[t] = z4;
        gemm64h(Hf, wfB, rowA, g, lane, acc2);
        #pragma unroll
        for (int r = 0; r < 4; ++r) {
            const int grow = row0 + wm * 16 + g * 4 + r;
            if (grow < nrows) {
                short4v o;
                o[0] = (short)bf16_rne(acc2[0][r]);
                o[1] = (short)bf16_rne(acc2[1][r]);
                o[2] = (short)bf16_rne(acc2[2][r]);
                o[3] = (short)bf16_rne(acc2[3][r]);
                *reinterpret_cast<short4v*>(u + (long long)grow * 64 + c4) = o;
            }
        }
        #pragma unroll
        for (int t = 0; t < 4; ++t) acc2[t] = z4;
        gemm64h(Hf, wfC, rowA, g, lane, acc2);
        #pragma unroll
        for (int r = 0; r < 4; ++r) {
            const int grow = row0 + wm * 16 + g * 4 + r;
            if (grow < nrows) {
                short4v o;
                o[0] = (short)bf16_rne(acc2[0][r]);
                o[1] = (short)bf16_rne(acc2[1][r]);
                o[2] = (short)bf16_rne(acc2[2][r]);
                o[3] = (short)bf16_rne(acc2[3][r]);
                *reinterpret_cast<short4v*>(v + (long long)grow * 64 + c4) = o;
            }
        }
    }
}

// ---------------- edge update: e(bf16) += LN(lrelu(lrelu(e@A + u[s] + v[r] + b1)@W2 + b2)) ----
__global__ __launch_bounds__(256, 8) void k_edge_mf(
    unsigned short* ebf, const int* __restrict__ sp, const int* __restrict__ rp,
    const unsigned short* __restrict__ u, const unsigned short* __restrict__ v,
    const short* __restrict__ wfA, const short* __restrict__ wfW2,
    const float* __restrict__ b1, const float* __restrict__ b2,
    const float* __restrict__ gam, const float* __restrict__ bet, int E)
{
    __shared__ short Hf[4096];
    const int row0 = blockIdx.x * 64;
    const int lane = threadIdx.x & 63;
    const int wm = threadIdx.x >> 6;
    const int g = lane >> 4, c = lane & 15;
    const int c4 = c << 2;
    const int rowA = wm * 16 + c;

    int sidx[4], ridx[4];
    #pragma unroll
    for (int r = 0; r < 4; ++r) {
        const int grow = row0 + wm * 16 + g * 4 + r;
        if (grow < E) { sidx[r] = sp[grow]; ridx[r] = rp[grow]; }
        else          { sidx[r] = 0; ridx[r] = 0; }
    }
    const int arow = (row0 + rowA < E) ? row0 + rowA : 0;
    const short8v a0 = *reinterpret_cast<const short8v*>(ebf + (long long)arow * 64 + g * 8);
    const short8v a1 = *reinterpret_cast<const short8v*>(ebf + (long long)arow * 64 + 32 + g * 8);
    short4v eold[4];
    #pragma unroll
    for (int r = 0; r < 4; ++r) {
        const int grow = row0 + wm * 16 + g * 4 + r;
        const int rc = (grow < E) ? grow : 0;
        eold[r] = *reinterpret_cast<const short4v*>(ebf + (long long)rc * 64 + c4);
    }
    short4v us[4], vs[4];
    #pragma unroll
    for (int r = 0; r < 4; ++r) {
        us[r] = *reinterpret_cast<const short4v*>(u + (long long)sidx[r] * 64 + c4);
        vs[r] = *reinterpret_cast<const short4v*>(v + (long long)ridx[r] * 64 + c4);
    }

    const f32x4 z4 = {0.f, 0.f, 0.f, 0.f};
    f32x4 acc[4];
    #pragma unroll
    for (int t = 0; t < 4; ++t) acc[t] = z4;
    #pragma unroll
    for (int s = 0; s < 2; ++s) {
        const short8v a = s ? a1 : a0;
        #pragma unroll
        for (int t = 0; t < 4; ++t) {
            const short8v b_hi = *reinterpret_cast<const short8v*>(wfA + ((s*4+t)*2+0)*512 + lane*8);
            const short8v b_lo = *reinterpret_cast<const short8v*>(wfA + ((s*4+t)*2+1)*512 + lane*8);
            acc[t] = __builtin_amdgcn_mfma_f32_16x16x32_bf16(a, b_hi, acc[t], 0, 0, 0);
            acc[t] = __builtin_amdgcn_mfma_f32_16x16x32_bf16(a, b_lo, acc[t], 0, 0, 0);
        }
    }

    const float4 b1q = *reinterpret_cast<const float4*>(b1 + c4);
    float4 hq[4];
    #pragma unroll
    for (int r = 0; r < 4; ++r) {
        hq[r].x = lrelu(acc[0][r] + b1q.x + bf16_to_f((unsigned short)us[r][0]) + bf16_to_f((unsigned short)vs[r][0]));
        hq[r].y = lrelu(acc[1][r] + b1q.y + bf16_to_f((unsigned short)us[r][1]) + bf16_to_f((unsigned short)vs[r][1]));
        hq[r].z = lrelu(acc[2][r] + b1q.z + bf16_to_f((unsigned short)us[r][2]) + bf16_to_f((unsigned short)vs[r][2]));
        hq[r].w = lrelu(acc[3][r] + b1q.w + bf16_to_f((unsigned short)us[r][3]) + bf16_to_f((unsigned short)vs[r][3]));
    }
    repack1(Hf, hq, wm, g, c4);
    __builtin_amdgcn_wave_barrier();

    f32x4 acc2[4];
    #pragma unroll
    for (int t = 0; t < 4; ++t) acc2[t] = z4;
    gemm64h(Hf, wfW2, rowA, g, lane, acc2);

    const float4 b2q = *reinterpret_cast<const float4*>(b2 + c4);
    const float b2a[4] = {b2q.x, b2q.y, b2q.z, b2q.w};
    #pragma unroll
    for (int t = 0; t < 4; ++t) {
        #pragma unroll
        for (int r = 0; r < 4; ++r) acc2[t][r] = lrelu(acc2[t][r] + b2a[t]);
    }
    const float4 gq = *reinterpret_cast<const float4*>(gam + c4);
    const float4 bq = *reinterpret_cast<const float4*>(bet + c4);
    #pragma unroll
    for (int r = 0; r < 4; ++r) {
        float s = acc2[0][r] + acc2[1][r] + acc2[2][r] + acc2[3][r];
        s += __shfl_xor(s, 1); s += __shfl_xor(s, 2); s += __shfl_xor(s, 4); s += __shfl_xor(s, 8);
        const float mu = s * 0.015625f;
        float q = 0.f;
        #pragma unroll
        for (int t = 0; t < 4; ++t) { const float d = acc2[t][r] - mu; q = fmaf(d, d, q); }
        q += __shfl_xor(q, 1); q += __shfl_xor(q, 2); q += __shfl_xor(q, 4); q += __shfl_xor(q, 8);
        const float rs = rsqrtf(q * 0.015625f + 1e-5f);
        const int grow = row0 + wm * 16 + g * 4 + r;
        if (grow < E) {
            float ox = (acc2[0][r] - mu) * rs * gq.x + bq.x + bf16_to_f((unsigned short)eold[r][0]);
            float oy = (acc2[1][r] - mu) * rs * gq.y + bq.y + bf16_to_f((unsigned short)eold[r][1]);
            float oz = (acc2[2][r] - mu) * rs * gq.z + bq.z + bf16_to_f((unsigned short)eold[r][2]);
            float ow = (acc2[3][r] - mu) * rs * gq.w + bq.w + bf16_to_f((unsigned short)eold[r][3]);
            short4v st;
            st[0] = (short)bf16_rne(ox);
            st[1] = (short)bf16_rne(oy);
            st[2] = (short)bf16_rne(oz);
            st[3] = (short)bf16_rne(ow);
            *reinterpret_cast<short4v*>(ebf + (long long)grow * 64 + c4) = st;
        }
    }
}

// ---------------- aggregation: wave per node, lane = column, coalesced bf16 CSR scan ----------------
__global__ __launch_bounds__(256, 8) void k_aggr(
    const unsigned short* __restrict__ ebf, const int* __restrict__ starts,
    const int* __restrict__ cnt, float* __restrict__ aggr, int N)
{
    const int node = blockIdx.x * 4 + (threadIdx.x >> 6);
    if (node >= N) return;
    const int j = threadIdx.x & 63;
    const int st = starts[node], en = st + cnt[node];
    float a = 0.f;
    for (int t = st; t < en; ++t)
        a += bf16_to_f(ebf[(long long)t * 64 + j]);
    aggr[(long long)node * 64 + j] = a;
}

// ---------------- node update: n += MLP(concat[n, aggr]); fused uv (bf16) for next layer ----------------
__global__ __launch_bounds__(256, 4) void k_node_mf(
    float* n, const float* aggr,
    const short* __restrict__ wfW1a, const short* __restrict__ wfW1b, const short* __restrict__ wfW2,
    const float* __restrict__ b1, const float* __restrict__ b2,
    const float* __restrict__ gam, const float* __restrict__ bet,
    const short* __restrict__ wfB, const short* __restrict__ wfC,
    unsigned short* __restrict__ u, unsigned short* __restrict__ v, int N)
{
    __shared__ short An[8192];
    __shared__ short Aa[8192];
    const int row0 = blockIdx.x * 64;
    const int lane = threadIdx.x & 63;
    const int wm = threadIdx.x >> 6;
    const int g = lane >> 4, c = lane & 15;
    const int c4 = c << 2;
    const int rowA = wm * 16 + c;

    stageW(n, row0, N, An, wm, lane);
    stageW(aggr, row0, N, Aa, wm, lane);
    __builtin_amdgcn_wave_barrier();

    const f32x4 z4 = {0.f, 0.f, 0.f, 0.f};
    f32x4 acc[4];
    #pragma unroll
    for (int t = 0; t < 4; ++t) acc[t] = z4;
    gemm64(An, wfW1a, rowA, g, lane, acc);
    gemm64(Aa, wfW1b, rowA, g, lane, acc);

    const float4 b1q = *reinterpret_cast<const float4*>(b1 + c4);
    float4 hq[4];
    #pragma unroll
    for (int r = 0; r < 4; ++r) {
        hq[r].x = lrelu(acc[0][r] + b1q.x);
        hq[r].y = lrelu(acc[1][r] + b1q.y);
        hq[r].z = lrelu(acc[2][r] + b1q.z);
        hq[r].w = lrelu(acc[3][r] + b1q.w);
    }
    __builtin_amdgcn_wave_barrier();
    repack1(Aa, hq, wm, g, c4);        // Aa dead after gemm -> overlay (hi plane only)
    __builtin_amdgcn_wave_barrier();

    f32x4 acc2[4];
    #pragma unroll
    for (int t = 0; t < 4; ++t) acc2[t] = z4;
    gemm64h(Aa, wfW2, rowA, g, lane, acc2);

    const float4 b2q = *reinterpret_cast<const float4*>(b2 + c4);
    const float b2a[4] = {b2q.x, b2q.y, b2q.z, b2q.w};
    #pragma unroll
    for (int t = 0; t < 4; ++t) {
        #pragma unroll
        for (int r = 0; r < 4; ++r) acc2[t][r] = lrelu(acc2[t][r] + b2a[t]);
    }
    const float4 gq = *reinterpret_cast<const float4*>(gam + c4);
    const float4 bq = *reinterpret_cast<const float4*>(bet + c4);
    float4 nq[4];
    #pragma unroll
    for (int r = 0; r < 4; ++r) {
        float s = acc2[0][r] + acc2[1][r] + acc2[2][r] + acc2[3][r];
        s += __shfl_xor(s, 1); s += __shfl_xor(s, 2); s += __shfl_xor(s, 4); s += __shfl_xor(s, 8);
        const float mu = s * 0.015625f;
        float q = 0.f;
        #pragma unroll
        for (int t = 0; t < 4; ++t) { const float d = acc2[t][r] - mu; q = fmaf(d, d, q); }
        q += __shfl_xor(q, 1); q += __shfl_xor(q, 2); q += __shfl_xor(q, 4); q += __shfl_xor(q, 8);
        const float rs = rsqrtf(q * 0.015625f + 1e-5f);
        const int rl = wm * 16 + g * 4 + r;
        const int off = rl * 64 + (((c4 >> 3) ^ (rl & 7)) << 3) + (c4 & 7);
        const short4v nh = *reinterpret_cast<const short4v*>(An + off);
        const short4v nl = *reinterpret_cast<const short4v*>(An + 4096 + off);
        nq[r].x = (acc2[0][r] - mu) * rs * gq.x + bq.x + bf16_to_f((unsigned short)nh[0]) + bf16_to_f((unsigned short)nl[0]);
        nq[r].y = (acc2[1][r] - mu) * rs * gq.y + bq.y + bf16_to_f((unsigned short)nh[1]) + bf16_to_f((unsigned short)nl[1]);
        nq[r].z = (acc2[2][r] - mu) * rs * gq.z + bq.z + bf16_to_f((unsigned short)nh[2]) + bf16_to_f((unsigned short)nl[2]);
        nq[r].w = (acc2[3][r] - mu) * rs * gq.w + bq.w + bf16_to_f((unsigned short)nh[3]) + bf16_to_f((unsigned short)nl[3]);
        const int grow = row0 + rl;
        if (grow < N)
            *reinterpret_cast<float4*>(n + (long long)grow * 64 + c4) = nq[r];
    }

    if (wfB) {
        __builtin_amdgcn_wave_barrier();
        repack1(An, nq, wm, g, c4);    // An residual consumed -> overlay hi plane with n_new
        __builtin_amdgcn_wave_barrier();
        #pragma unroll
        for (int t = 0; t < 4; ++t) acc2[t] = z4;
        gemm64h(An, wfB, rowA, g, lane, acc2);
        #pragma unroll
        for (int r = 0; r < 4; ++r) {
            const int grow = row0 + wm * 16 + g * 4 + r;
            if (grow < N) {
                short4v o;
                o[0] = (short)bf16_rne(acc2[0][r]);
                o[1] = (short)bf16_rne(acc2[1][r]);
                o[2] = (short)bf16_rne(acc2[2][r]);
                o[3] = (short)bf16_rne(acc2[3][r]);
                *reinterpret_cast<short4v*>(u + (long long)grow * 64 + c4) = o;
            }
        }
        #pragma unroll
        for (int t = 0; t < 4; ++t) acc2[t] = z4;
        gemm64h(An, wfC, rowA, g, lane, acc2);
        #pragma unroll
        for (int r = 0; r < 4; ++r) {
            const int grow = row0 + wm * 16 + g * 4 + r;
            if (grow < N) {
                short4v o;
                o[0] = (short)bf16_rne(acc2[0][r]);
                o[1] = (short)bf16_rne(acc2[1][r]);
                o[2] = (short)bf16_rne(acc2[2][r]);
                o[3] = (short)bf16_rne(acc2[3][r]);
                *reinterpret_cast<short4v*>(v + (long long)grow * 64 + c4) = o;
            }
        }
    }
}

// ---------------- decoder: per-wave, shfl-reduce tail (OUT=3) ----------------
__global__ __launch_bounds__(256, 4) void k_dec_mf(
    const float* __restrict__ n, const short* __restrict__ wfW1, const float* __restrict__ b1,
    const float* __restrict__ W2, const float* __restrict__ b2,
    float* __restrict__ out, int N)
{
    __shared__ short An[8192];
    const int row0 = blockIdx.x * 64;
    const int lane = threadIdx.x & 63;
    const int wm = threadIdx.x >> 6;
    const int g = lane >> 4, c = lane & 15;
    const int c4 = c << 2;
    const int rowA = wm * 16 + c;
    stageW(n, row0, N, An, wm, lane);
    __builtin_amdgcn_wave_barrier();
    const f32x4 z4 = {0.f, 0.f, 0.f, 0.f};
    f32x4 acc[4];
    #pragma unroll
    for (int t = 0; t < 4; ++t) acc[t] = z4;
    gemm64(An, wfW1, rowA, g, lane, acc);
    const float4 b1q = *reinterpret_cast<const float4*>(b1 + c4);
    const float b1a[4] = {b1q.x, b1q.y, b1q.z, b1q.w};
    #pragma unroll
    for (int t = 0; t < 4; ++t)
        #pragma unroll
        for (int r = 0; r < 4; ++r) acc[t][r] = lrelu(acc[t][r] + b1a[t]);
    const float4 w0 = *reinterpret_cast<const float4*>(W2 + c4 * 3);
    const float4 w1 = *reinterpret_cast<const float4*>(W2 + c4 * 3 + 4);
    const float4 w2 = *reinterpret_cast<const float4*>(W2 + c4 * 3 + 8);
    const float wv[12] = {w0.x,w0.y,w0.z,w0.w, w1.x,w1.y,w1.z,w1.w, w2.x,w2.y,w2.z,w2.w};
    float po[4][3];
    #pragma unroll
    for (int r = 0; r < 4; ++r)
        #pragma unroll
        for (int o = 0; o < 3; ++o)
            po[r][o] = acc[0][r]*wv[o] + acc[1][r]*wv[3+o] + acc[2][r]*wv[6+o] + acc[3][r]*wv[9+o];
    #pragma unroll
    for (int m = 1; m <= 8; m <<= 1)
        #pragma unroll
        for (int r = 0; r < 4; ++r)
            #pragma unroll
            for (int o = 0; o < 3; ++o)
                po[r][o] += __shfl_xor(po[r][o], m);
    if (c < 3) {
        #pragma unroll
        for (int r = 0; r < 4; ++r) {
            const int grow = row0 + wm * 16 + g * 4 + r;
            const float val = (c == 0) ? po[r][0] : (c == 1) ? po[r][1] : po[r][2];
            if (grow < N) out[(long long)grow * 3 + c] = b2[c] + val;
        }
    }
}

// ================= CSR build =================
__global__ void k_hist(const int* __restrict__ eidx, int* __restrict__ cnt, int E)
{
    int i = blockIdx.x * 256 + threadIdx.x;
    if (i < E) atomicAdd(&cnt[eidx[2 * i]], 1);
}

__global__ void k_scan1(const int* __restrict__ cnt, int* __restrict__ starts,
                        int* __restrict__ bsum, int n)
{
    __shared__ int sh[256];
    const int tid = threadIdx.x;
    const int i = blockIdx.x * 256 + tid;
    const int val = (i < n) ? cnt[i] : 0;
    sh[tid] = val; __syncthreads();
    for (int off = 1; off < 256; off <<= 1) {
        int t = (tid >= off) ? sh[tid - off] : 0;
        __syncthreads();
        sh[tid] += t;
        __syncthreads();
    }
    if (i < n) starts[i] = sh[tid] - val;
    if (tid == 255) bsum[blockIdx.x] = sh[255];
}

__global__ void k_scan2(int* __restrict__ bsum, int nb)
{
    __shared__ int sh[256];
    const int tid = threadIdx.x;
    const int val = (tid < nb) ? bsum[tid] : 0;
    sh[tid] = val; __syncthreads();
    for (int off = 1; off < 256; off <<= 1) {
        int t = (tid >= off) ? sh[tid - off] : 0;
        __syncthreads();
        sh[tid] += t;
        __syncthreads();
    }
    if (tid < nb) bsum[tid] = sh[tid] - val;
}

__global__ void k_scan3(int* __restrict__ starts, const int* __restrict__ bsum, int n)
{
    int i = blockIdx.x * 256 + threadIdx.x;
    if (i < n) starts[i] += bsum[blockIdx.x];
}

__global__ void k_scatter(const int* __restrict__ eidx, const int* __restrict__ starts,
                          int* __restrict__ cursor, int* __restrict__ csr,
                          int* __restrict__ sp, int* __restrict__ rp, int E)
{
    int i = blockIdx.x * 256 + threadIdx.x;
    if (i < E) {
        const int s = eidx[2 * i];
        const int p = atomicAdd(&cursor[s], 1);
        const int q = starts[s] + p;
        csr[q] = i;
        sp[q] = s;
        rp[q] = eidx[2 * i + 1];
    }
}

extern "C" void kernel_launch(void* const* d_in, const int* in_sizes, int n_in,
                              void* d_out, int out_size, void* d_ws, size_t ws_size,
                              hipStream_t stream)
{
    (void)in_sizes; (void)n_in; (void)out_size; (void)ws_size;
    constexpr int N = 50000, E = 300000, L = 3;

    const float* nodes = (const float*)d_in[0];
    const float* edges = (const float*)d_in[1];
    const int*   eidx  = (const int*)d_in[2];
    const float* neW1 = (const float*)d_in[3];
    const float* neb1 = (const float*)d_in[4];
    const float* neW2 = (const float*)d_in[5];
    const float* neb2 = (const float*)d_in[6];
    const float* neg  = (const float*)d_in[7];
    const float* nebe = (const float*)d_in[8];
    const float* eeW1 = (const float*)d_in[9];
    const float* eeb1 = (const float*)d_in[10];
    const float* eeW2 = (const float*)d_in[11];
    const float* eeb2 = (const float*)d_in[12];
    const float* eeg  = (const float*)d_in[13];
    const float* eebe = (const float*)d_in[14];
    const float* nmW1 = (const float*)d_in[15];
    const float* nmb1 = (const float*)d_in[16];
    const float* nmW2 = (const float*)d_in[17];
    const float* nmb2 = (const float*)d_in[18];
    const float* nmg  = (const float*)d_in[19];
    const float* nmbe = (const float*)d_in[20];
    const float* emW1 = (const float*)d_in[21];
    const float* emb1 = (const float*)d_in[22];
    const float* emW2 = (const float*)d_in[23];
    const float* emb2 = (const float*)d_in[24];
    const float* emg  = (const float*)d_in[25];
    const float* embe = (const float*)d_in[26];
    const float* decW1 = (const float*)d_in[27];
    const float* decb1 = (const float*)d_in[28];
    const float* decW2 = (const float*)d_in[29];
    const float* decb2 = (const float*)d_in[30];

    // workspace: n(f32) | aggr(f32) | ubf | vbf | ints | wf | ebf
    float* n    = (float*)d_ws;                       // N*64 f32
    float* aggr = n + (size_t)N * 64;                 // N*64 f32
    unsigned short* ubf = (unsigned short*)(aggr + (size_t)N * 64);  // N*64 bf16
    unsigned short* vbf = ubf + (size_t)N * 64;       // N*64 bf16
    int* cnt    = (int*)(vbf + (size_t)N * 64);       // N
    int* starts = cnt + N;                            // N
    int* csr    = starts + N;                         // E
    int* bsum   = csr + E;                            // 256
    int* cursor = bsum + 256;                         // N
    int* sp     = cursor + N;                         // E
    int* rp     = sp + E;                             // E
    short* wf   = (short*)(rp + E);                   // 24 * 8192 shorts
    unsigned short* ebf = (unsigned short*)(wf + (size_t)24 * 8192);  // E*64 bf16

    const int nbN = (N + 255) / 256;
    const int nbE = (E + 255) / 256;
    const int nbN64 = (N + 63) / 64;            // 782
    const int nbE64 = (E + 63) / 64;            // 4688

    const short* wfEE  = wf + (size_t)21 * 8192;
    const short* wfNE  = wf + (size_t)22 * 8192;
    const short* wfDec = wf + (size_t)23 * 8192;

    // ---- weight fragment prep + CSR build ----
    k_prepw<<<24, 256, 0, stream>>>(emW1, emW2, nmW1, nmW2, eeW2, neW2, decW1, wf);
    hipMemsetAsync(cnt, 0, (size_t)N * sizeof(int), stream);
    hipMemsetAsync(cursor, 0, (size_t)N * sizeof(int), stream);
    k_hist<<<nbE, 256, 0, stream>>>(eidx, cnt, E);
    k_scan1<<<nbN, 256, 0, stream>>>(cnt, starts, bsum, N);
    k_scan2<<<1, 256, 0, stream>>>(bsum, nbN);
    k_scan3<<<nbN, 256, 0, stream>>>(starts, bsum, N);
    k_scatter<<<nbE, 256, 0, stream>>>(eidx, starts, cursor, csr, sp, rp, E);

    // ---- encode (node encoder also emits u,v for layer 0; edge encoder writes bf16 e) ----
    const short* wl0 = wf;
    k_enc_mf<16, false, true, false><<<nbN64, 256, 0, stream>>>(
        nodes, nullptr, neW1, neb1, wfNE, neb2, neg, nebe, n,
        wl0 + 8192, wl0 + 2 * 8192, ubf, vbf, N);
    k_enc_mf<8, true, false, true><<<nbE64, 256, 0, stream>>>(
        edges, csr, eeW1, eeb1, wfEE, eeb2, eeg, eebe, (float*)ebf,
        nullptr, nullptr, nullptr, nullptr, E);

    // ---- message-passing layers ----
    for (int i = 0; i < L; ++i) {
        const short* wl = wf + (size_t)i * 7 * 8192;
        k_edge_mf<<<nbE64, 256, 0, stream>>>(ebf, sp, rp, ubf, vbf, wl, wl + 3 * 8192,
                                             emb1 + i * 64, emb2 + i * 64,
                                             emg + i * 64, embe + i * 64, E);
        k_aggr<<<(N + 3) / 4, 256, 0, stream>>>(ebf, starts, cnt, aggr, N);
        const short* wln = (i + 1 < L) ? wf + (size_t)(i + 1) * 7 * 8192 : nullptr;
        k_node_mf<<<nbN64, 256, 0, stream>>>(n, aggr,
                                             wl + 4 * 8192, wl + 5 * 8192, wl + 6 * 8192,
                                             nmb1 + i * 64, nmb2 + i * 64,
                                             nmg + i * 64, nmbe + i * 64,
                                             wln ? wln + 8192 : nullptr,
                                             wln ? wln + 2 * 8192 : nullptr,
                                             ubf, vbf, N);
    }
    k_dec_mf<<<nbN64, 256, 0, stream>>>(n, wfDec, decb1, decW2, decb2, (float*)d_out, N);
}

// Round 14
// 415.240 us; speedup vs baseline: 1.1192x; 1.1192x over previous
//
#include <hip/hip_runtime.h>

typedef __attribute__((ext_vector_type(8))) short short8v;
typedef __attribute__((ext_vector_type(4))) short short4v;
typedef __attribute__((ext_vector_type(4))) float f32x4;

__device__ __forceinline__ float lrelu(float x) { return x >= 0.f ? x : 0.05f * x; }

__device__ __forceinline__ unsigned short bf16_rne(float x) {
    unsigned u = __float_as_uint(x);
    u += 0x7FFFu + ((u >> 16) & 1u);
    return (unsigned short)(u >> 16);
}
__device__ __forceinline__ float bf16_to_f(unsigned short h) {
    return __uint_as_float(((unsigned)h) << 16);
}
__device__ __forceinline__ void split2(float x, unsigned short& hi, unsigned short& lo) {
    hi = bf16_rne(x);
    lo = bf16_rne(x - bf16_to_f(hi));
}

// ================= MFMA machinery =================
// A-frag (M=16,K=32): lane holds A[row=lane&15][k=(lane>>4)*8+i]
// B-frag: lane holds B[k][frag col16=lane&15]; COLUMN INTERLEAVE: frag t, col16 c -> global col 4c+t.
// C/D: col16=lane&15, row=(lane>>4)*4+reg
// LDS A layout per plane: A[row][k] shorts, 16B slots XOR-swizzled: slot=(k>>3)^(row&7); lo plane at +4096.
// Precision: weights hi/lo; staged fp32 tensors (n, aggr) hi/lo; e/u/v global bf16;
// hidden activations H single bf16.
// Round-13/14 lesson: launch_bounds occupancy raise works ONLY where VGPR use fits the cap
// (k_edge 44<=64 at (256,8): WIN). Encoders spilled at (256,6) -> keep (256,4).

__device__ __forceinline__ void stageW(const float* src, int row0, int nrows,
                                       short* __restrict__ A, int wm, int lane)
{
    #pragma unroll
    for (int it = 0; it < 4; ++it) {
        const int q = it * 64 + lane;
        const int rl = wm * 16 + (q >> 4);
        const int k0 = (q & 15) << 2;
        const int grow = row0 + rl;
        float4 x = (grow < nrows) ? *reinterpret_cast<const float4*>(src + (long long)grow * 64 + k0)
                                  : make_float4(0.f, 0.f, 0.f, 0.f);
        unsigned short h0,h1,h2,h3,l0,l1,l2,l3;
        split2(x.x, h0, l0); split2(x.y, h1, l1); split2(x.z, h2, l2); split2(x.w, h3, l3);
        const int off = rl * 64 + ((((k0 >> 3) ^ (rl & 7))) << 3) + (k0 & 7);
        short4v hv; hv[0]=(short)h0; hv[1]=(short)h1; hv[2]=(short)h2; hv[3]=(short)h3;
        short4v lv; lv[0]=(short)l0; lv[1]=(short)l1; lv[2]=(short)l2; lv[3]=(short)l3;
        *reinterpret_cast<short4v*>(A + off) = hv;
        *reinterpret_cast<short4v*>(A + 4096 + off) = lv;
    }
}

__device__ __forceinline__ void gemm64(const short* __restrict__ A, const short* __restrict__ wf,
                                       int row, int g, int lane, f32x4* __restrict__ acc)
{
    #pragma unroll
    for (int s = 0; s < 2; ++s) {
        const int k8 = s * 4 + g;
        const int aoff = row * 64 + ((k8 ^ (row & 7)) << 3);
        const short8v a_hi = *reinterpret_cast<const short8v*>(A + aoff);
        const short8v a_lo = *reinterpret_cast<const short8v*>(A + 4096 + aoff);
        #pragma unroll
        for (int t = 0; t < 4; ++t) {
            const short8v b_hi = *reinterpret_cast<const short8v*>(wf + ((s*4+t)*2+0)*512 + lane*8);
            const short8v b_lo = *reinterpret_cast<const short8v*>(wf + ((s*4+t)*2+1)*512 + lane*8);
            acc[t] = __builtin_amdgcn_mfma_f32_16x16x32_bf16(a_hi, b_hi, acc[t], 0, 0, 0);
            acc[t] = __builtin_amdgcn_mfma_f32_16x16x32_bf16(a_lo, b_hi, acc[t], 0, 0, 0);
            acc[t] = __builtin_amdgcn_mfma_f32_16x16x32_bf16(a_hi, b_lo, acc[t], 0, 0, 0);
        }
    }
}

__device__ __forceinline__ void gemm64h(const short* __restrict__ A, const short* __restrict__ wf,
                                        int row, int g, int lane, f32x4* __restrict__ acc)
{
    #pragma unroll
    for (int s = 0; s < 2; ++s) {
        const int k8 = s * 4 + g;
        const int aoff = row * 64 + ((k8 ^ (row & 7)) << 3);
        const short8v a = *reinterpret_cast<const short8v*>(A + aoff);
        #pragma unroll
        for (int t = 0; t < 4; ++t) {
            const short8v b_hi = *reinterpret_cast<const short8v*>(wf + ((s*4+t)*2+0)*512 + lane*8);
            const short8v b_lo = *reinterpret_cast<const short8v*>(wf + ((s*4+t)*2+1)*512 + lane*8);
            acc[t] = __builtin_amdgcn_mfma_f32_16x16x32_bf16(a, b_hi, acc[t], 0, 0, 0);
            acc[t] = __builtin_amdgcn_mfma_f32_16x16x32_bf16(a, b_lo, acc[t], 0, 0, 0);
        }
    }
}

__device__ __forceinline__ void repack1(short* __restrict__ A, const float4* __restrict__ q,
                                        int wm, int g, int c4)
{
    #pragma unroll
    for (int r = 0; r < 4; ++r) {
        const int rl = wm * 16 + g * 4 + r;
        const int off = rl * 64 + (((c4 >> 3) ^ (rl & 7)) << 3) + (c4 & 7);
        short4v hv;
        hv[0] = (short)bf16_rne(q[r].x);
        hv[1] = (short)bf16_rne(q[r].y);
        hv[2] = (short)bf16_rne(q[r].z);
        hv[3] = (short)bf16_rne(q[r].w);
        *reinterpret_cast<short4v*>(A + off) = hv;
    }
}

// Preformat 64x64 fp32 W[k][col] chunks -> hi/lo B-fragments (interleaved col map).
__global__ void k_prepw(const float* __restrict__ emW1, const float* __restrict__ emW2,
                        const float* __restrict__ nmW1, const float* __restrict__ nmW2,
                        const float* __restrict__ eeW2, const float* __restrict__ neW2,
                        const float* __restrict__ decW1,
                        short* __restrict__ wf)
{
    const int cid = blockIdx.x;
    const float* src;
    if (cid < 21) {
        const int layer = cid / 7, j = cid % 7;
        src =
            j == 0 ? emW1 + (size_t)layer * 12288 :
            j == 1 ? emW1 + (size_t)layer * 12288 + 4096 :
            j == 2 ? emW1 + (size_t)layer * 12288 + 8192 :
            j == 3 ? emW2 + (size_t)layer * 4096 :
            j == 4 ? nmW1 + (size_t)layer * 8192 :
            j == 5 ? nmW1 + (size_t)layer * 8192 + 4096 :
                     nmW2 + (size_t)layer * 4096;
    } else {
        src = (cid == 21) ? eeW2 : (cid == 22) ? neW2 : decW1;
    }
    short* dst = wf + (size_t)cid * 8192;
    for (int fr = threadIdx.x; fr < 1024; fr += 256) {
        const int lane = fr & 63;
        const int stp = fr >> 6;
        const int p = stp & 1;
        const int st = stp >> 1;
        const int s = st >> 2, t = st & 3;
        const int col = ((lane & 15) << 2) + t;
        const int k0 = s * 32 + (lane >> 4) * 8;
        short8v o;
        #pragma unroll
        for (int i = 0; i < 8; ++i) {
            const float w = src[(k0 + i) * 64 + col];
            const unsigned short hi = bf16_rne(w);
            o[i] = (short)(p ? bf16_rne(w - bf16_to_f(hi)) : hi);
        }
        *reinterpret_cast<short8v*>(dst + fr * 8) = o;
    }
}

// ---------------- encoder; MAKEUV: also emit u,v (bf16); OUTBF16: bf16 output (edge stream) ----------------
template<int DIN, bool PERM, bool MAKEUV, bool OUTBF16>
__global__ __launch_bounds__(256, 4) void k_enc_mf(
    const float* __restrict__ x, const int* __restrict__ csr,
    const float* __restrict__ W1, const float* __restrict__ b1,
    const short* __restrict__ wfW2, const float* __restrict__ b2,
    const float* __restrict__ gam, const float* __restrict__ bet,
    float* __restrict__ out,
    const short* __restrict__ wfB, const short* __restrict__ wfC,
    unsigned short* __restrict__ u, unsigned short* __restrict__ v, int nrows)
{
    __shared__ short Hf[4096];
    const int row0 = blockIdx.x * 64;
    const int lane = threadIdx.x & 63;
    const int wm = threadIdx.x >> 6;
    const int g = lane >> 4, c = lane & 15;
    const int c4 = c << 2;
    const int rowA = wm * 16 + c;

    long long orig[4];
    #pragma unroll
    for (int r = 0; r < 4; ++r) {
        const int grow = row0 + wm * 16 + g * 4 + r;
        orig[r] = (grow < nrows) ? (long long)(PERM ? csr[grow] : grow) : -1;
    }

    const f32x4 z4 = {0.f, 0.f, 0.f, 0.f};
    f32x4 acc[4];
    #pragma unroll
    for (int t = 0; t < 4; ++t) acc[t] = z4;

    #pragma unroll
    for (int kq = 0; kq < DIN / 4; ++kq) {
        float xv[4][4];
        #pragma unroll
        for (int r = 0; r < 4; ++r) {
            float4 t4 = make_float4(0.f, 0.f, 0.f, 0.f);
            if (orig[r] >= 0)
                t4 = *reinterpret_cast<const float4*>(x + orig[r] * DIN + kq * 4);
            xv[r][0] = t4.x; xv[r][1] = t4.y; xv[r][2] = t4.z; xv[r][3] = t4.w;
        }
        #pragma unroll
        for (int i = 0; i < 4; ++i) {
            const int k = kq * 4 + i;
            const float4 w4 = *reinterpret_cast<const float4*>(W1 + k * 64 + c4);
            const float wv[4] = {w4.x, w4.y, w4.z, w4.w};
            #pragma unroll
            for (int t = 0; t < 4; ++t)
                #pragma unroll
                for (int r = 0; r < 4; ++r)
                    acc[t][r] = fmaf(xv[r][i], wv[t], acc[t][r]);
        }
    }

    const float4 b1q = *reinterpret_cast<const float4*>(b1 + c4);
    float4 hq[4];
    #pragma unroll
    for (int r = 0; r < 4; ++r) {
        hq[r].x = lrelu(acc[0][r] + b1q.x);
        hq[r].y = lrelu(acc[1][r] + b1q.y);
        hq[r].z = lrelu(acc[2][r] + b1q.z);
        hq[r].w = lrelu(acc[3][r] + b1q.w);
    }
    repack1(Hf, hq, wm, g, c4);
    __builtin_amdgcn_wave_barrier();

    f32x4 acc2[4];
    #pragma unroll
    for (int t = 0; t < 4; ++t) acc2[t] = z4;
    gemm64h(Hf, wfW2, rowA, g, lane, acc2);

    const float4 b2q = *reinterpret_cast<const float4*>(b2 + c4);
    const float b2a[4] = {b2q.x, b2q.y, b2q.z, b2q.w};
    #pragma unroll
    for (int t = 0; t < 4; ++t) {
        #pragma unroll
        for (int r = 0; r < 4; ++r) acc2[t][r] = lrelu(acc2[t][r] + b2a[t]);
    }
    const float4 gq = *reinterpret_cast<const float4*>(gam + c4);
    const float4 bq = *reinterpret_cast<const float4*>(bet + c4);
    float4 nq[4];
    #pragma unroll
    for (int r = 0; r < 4; ++r) {
        float s = acc2[0][r] + acc2[1][r] + acc2[2][r] + acc2[3][r];
        s += __shfl_xor(s, 1); s += __shfl_xor(s, 2); s += __shfl_xor(s, 4); s += __shfl_xor(s, 8);
        const float mu = s * 0.015625f;
        float q = 0.f;
        #pragma unroll
        for (int t = 0; t < 4; ++t) { const float d = acc2[t][r] - mu; q = fmaf(d, d, q); }
        q += __shfl_xor(q, 1); q += __shfl_xor(q, 2); q += __shfl_xor(q, 4); q += __shfl_xor(q, 8);
        const float rs = rsqrtf(q * 0.015625f + 1e-5f);
        nq[r].x = (acc2[0][r] - mu) * rs * gq.x + bq.x;
        nq[r].y = (acc2[1][r] - mu) * rs * gq.y + bq.y;
        nq[r].z = (acc2[2][r] - mu) * rs * gq.z + bq.z;
        nq[r].w = (acc2[3][r] - mu) * rs * gq.w + bq.w;
        const int grow = row0 + wm * 16 + g * 4 + r;
        if (grow < nrows) {
            if constexpr (OUTBF16) {
                short4v st;
                st[0] = (short)bf16_rne(nq[r].x);
                st[1] = (short)bf16_rne(nq[r].y);
                st[2] = (short)bf16_rne(nq[r].z);
                st[3] = (short)bf16_rne(nq[r].w);
                *reinterpret_cast<short4v*>(reinterpret_cast<unsigned short*>(out) + (long long)grow * 64 + c4) = st;
            } else {
                *reinterpret_cast<float4*>(out + (long long)grow * 64 + c4) = nq[r];
            }
        }
    }

    if constexpr (MAKEUV) {
        __builtin_amdgcn_wave_barrier();
        repack1(Hf, nq, wm, g, c4);
        __builtin_amdgcn_wave_barrier();
        #pragma unroll
        for (int t = 0; t < 4; ++t) acc2[t] = z4;
        gemm64h(Hf, wfB, rowA, g, lane, acc2);
        #pragma unroll
        for (int r = 0; r < 4; ++r) {
            const int grow = row0 + wm * 16 + g * 4 + r;
            if (grow < nrows) {
                short4v o;
                o[0] = (short)bf16_rne(acc2[0][r]);
                o[1] = (short)bf16_rne(acc2[1][r]);
                o[2] = (short)bf16_rne(acc2[2][r]);
                o[3] = (short)bf16_rne(acc2[3][r]);
                *reinterpret_cast<short4v*>(u + (long long)grow * 64 + c4) = o;
            }
        }
        #pragma unroll
        for (int t = 0; t < 4; ++t) acc2[t] = z4;
        gemm64h(Hf, wfC, rowA, g, lane, acc2);
        #pragma unroll
        for (int r = 0; r < 4; ++r) {
            const int grow = row0 + wm * 16 + g * 4 + r;
            if (grow < nrows) {
                short4v o;
                o[0] = (short)bf16_rne(acc2[0][r]);
                o[1] = (short)bf16_rne(acc2[1][r]);
                o[2] = (short)bf16_rne(acc2[2][r]);
                o[3] = (short)bf16_rne(acc2[3][r]);
                *reinterpret_cast<short4v*>(v + (long long)grow * 64 + c4) = o;
            }
        }
    }
}

// ---------------- edge update: e(bf16) += LN(lrelu(lrelu(e@A + u[s] + v[r] + b1)@W2 + b2)) ----
__global__ __launch_bounds__(256, 8) void k_edge_mf(
    unsigned short* ebf, const int* __restrict__ sp, const int* __restrict__ rp,
    const unsigned short* __restrict__ u, const unsigned short* __restrict__ v,
    const short* __restrict__ wfA, const short* __restrict__ wfW2,
    const float* __restrict__ b1, const float* __restrict__ b2,
    const float* __restrict__ gam, const float* __restrict__ bet, int E)
{
    __shared__ short Hf[4096];
    const int row0 = blockIdx.x * 64;
    const int lane = threadIdx.x & 63;
    const int wm = threadIdx.x >> 6;
    const int g = lane >> 4, c = lane & 15;
    const int c4 = c << 2;
    const int rowA = wm * 16 + c;

    int sidx[4], ridx[4];
    #pragma unroll
    for (int r = 0; r < 4; ++r) {
        const int grow = row0 + wm * 16 + g * 4 + r;
        if (grow < E) { sidx[r] = sp[grow]; ridx[r] = rp[grow]; }
        else          { sidx[r] = 0; ridx[r] = 0; }
    }
    const int arow = (row0 + rowA < E) ? row0 + rowA : 0;
    const short8v a0 = *reinterpret_cast<const short8v*>(ebf + (long long)arow * 64 + g * 8);
    const short8v a1 = *reinterpret_cast<const short8v*>(ebf + (long long)arow * 64 + 32 + g * 8);
    short4v eold[4];
    #pragma unroll
    for (int r = 0; r < 4; ++r) {
        const int grow = row0 + wm * 16 + g * 4 + r;
        const int rc = (grow < E) ? grow : 0;
        eold[r] = *reinterpret_cast<const short4v*>(ebf + (long long)rc * 64 + c4);
    }
    short4v us[4], vs[4];
    #pragma unroll
    for (int r = 0; r < 4; ++r) {
        us[r] = *reinterpret_cast<const short4v*>(u + (long long)sidx[r] * 64 + c4);
        vs[r] = *reinterpret_cast<const short4v*>(v + (long long)ridx[r] * 64 + c4);
    }

    const f32x4 z4 = {0.f, 0.f, 0.f, 0.f};
    f32x4 acc[4];
    #pragma unroll
    for (int t = 0; t < 4; ++t) acc[t] = z4;
    #pragma unroll
    for (int s = 0; s < 2; ++s) {
        const short8v a = s ? a1 : a0;
        #pragma unroll
        for (int t = 0; t < 4; ++t) {
            const short8v b_hi = *reinterpret_cast<const short8v*>(wfA + ((s*4+t)*2+0)*512 + lane*8);
            const short8v b_lo = *reinterpret_cast<const short8v*>(wfA + ((s*4+t)*2+1)*512 + lane*8);
            acc[t] = __builtin_amdgcn_mfma_f32_16x16x32_bf16(a, b_hi, acc[t], 0, 0, 0);
            acc[t] = __builtin_amdgcn_mfma_f32_16x16x32_bf16(a, b_lo, acc[t], 0, 0, 0);
        }
    }

    const float4 b1q = *reinterpret_cast<const float4*>(b1 + c4);
    float4 hq[4];
    #pragma unroll
    for (int r = 0; r < 4; ++r) {
        hq[r].x = lrelu(acc[0][r] + b1q.x + bf16_to_f((unsigned short)us[r][0]) + bf16_to_f((unsigned short)vs[r][0]));
        hq[r].y = lrelu(acc[1][r] + b1q.y + bf16_to_f((unsigned short)us[r][1]) + bf16_to_f((unsigned short)vs[r][1]));
        hq[r].z = lrelu(acc[2][r] + b1q.z + bf16_to_f((unsigned short)us[r][2]) + bf16_to_f((unsigned short)vs[r][2]));
        hq[r].w = lrelu(acc[3][r] + b1q.w + bf16_to_f((unsigned short)us[r][3]) + bf16_to_f((unsigned short)vs[r][3]));
    }
    repack1(Hf, hq, wm, g, c4);
    __builtin_amdgcn_wave_barrier();

    f32x4 acc2[4];
    #pragma unroll
    for (int t = 0; t < 4; ++t) acc2[t] = z4;
    gemm64h(Hf, wfW2, rowA, g, lane, acc2);

    const float4 b2q = *reinterpret_cast<const float4*>(b2 + c4);
    const float b2a[4] = {b2q.x, b2q.y, b2q.z, b2q.w};
    #pragma unroll
    for (int t = 0; t < 4; ++t) {
        #pragma unroll
        for (int r = 0; r < 4; ++r) acc2[t][r] = lrelu(acc2[t][r] + b2a[t]);
    }
    const float4 gq = *reinterpret_cast<const float4*>(gam + c4);
    const float4 bq = *reinterpret_cast<const float4*>(bet + c4);
    #pragma unroll
    for (int r = 0; r < 4; ++r) {
        float s = acc2[0][r] + acc2[1][r] + acc2[2][r] + acc2[3][r];
        s += __shfl_xor(s, 1); s += __shfl_xor(s, 2); s += __shfl_xor(s, 4); s += __shfl_xor(s, 8);
        const float mu = s * 0.015625f;
        float q = 0.f;
        #pragma unroll
        for (int t = 0; t < 4; ++t) { const float d = acc2[t][r] - mu; q = fmaf(d, d, q); }
        q += __shfl_xor(q, 1); q += __shfl_xor(q, 2); q += __shfl_xor(q, 4); q += __shfl_xor(q, 8);
        const float rs = rsqrtf(q * 0.015625f + 1e-5f);
        const int grow = row0 + wm * 16 + g * 4 + r;
        if (grow < E) {
            float ox = (acc2[0][r] - mu) * rs * gq.x + bq.x + bf16_to_f((unsigned short)eold[r][0]);
            float oy = (acc2[1][r] - mu) * rs * gq.y + bq.y + bf16_to_f((unsigned short)eold[r][1]);
            float oz = (acc2[2][r] - mu) * rs * gq.z + bq.z + bf16_to_f((unsigned short)eold[r][2]);
            float ow = (acc2[3][r] - mu) * rs * gq.w + bq.w + bf16_to_f((unsigned short)eold[r][3]);
            short4v st;
            st[0] = (short)bf16_rne(ox);
            st[1] = (short)bf16_rne(oy);
            st[2] = (short)bf16_rne(oz);
            st[3] = (short)bf16_rne(ow);
            *reinterpret_cast<short4v*>(ebf + (long long)grow * 64 + c4) = st;
        }
    }
}

// ---------------- aggregation: wave per node, lane = column, coalesced bf16 CSR scan ----------------
__global__ __launch_bounds__(256, 8) void k_aggr(
    const unsigned short* __restrict__ ebf, const int* __restrict__ starts,
    const int* __restrict__ cnt, float* __restrict__ aggr, int N)
{
    const int node = blockIdx.x * 4 + (threadIdx.x >> 6);
    if (node >= N) return;
    const int j = threadIdx.x & 63;
    const int st = starts[node], en = st + cnt[node];
    float a = 0.f;
    for (int t = st; t < en; ++t)
        a += bf16_to_f(ebf[(long long)t * 64 + j]);
    aggr[(long long)node * 64 + j] = a;
}

// ---------------- node update: n += MLP(concat[n, aggr]); fused uv (bf16) for next layer ----------------
__global__ __launch_bounds__(256, 4) void k_node_mf(
    float* n, const float* aggr,
    const short* __restrict__ wfW1a, const short* __restrict__ wfW1b, const short* __restrict__ wfW2,
    const float* __restrict__ b1, const float* __restrict__ b2,
    const float* __restrict__ gam, const float* __restrict__ bet,
    const short* __restrict__ wfB, const short* __restrict__ wfC,
    unsigned short* __restrict__ u, unsigned short* __restrict__ v, int N)
{
    __shared__ short An[8192];
    __shared__ short Aa[8192];
    const int row0 = blockIdx.x * 64;
    const int lane = threadIdx.x & 63;
    const int wm = threadIdx.x >> 6;
    const int g = lane >> 4, c = lane & 15;
    const int c4 = c << 2;
    const int rowA = wm * 16 + c;

    stageW(n, row0, N, An, wm, lane);
    stageW(aggr, row0, N, Aa, wm, lane);
    __builtin_amdgcn_wave_barrier();

    const f32x4 z4 = {0.f, 0.f, 0.f, 0.f};
    f32x4 acc[4];
    #pragma unroll
    for (int t = 0; t < 4; ++t) acc[t] = z4;
    gemm64(An, wfW1a, rowA, g, lane, acc);
    gemm64(Aa, wfW1b, rowA, g, lane, acc);

    const float4 b1q = *reinterpret_cast<const float4*>(b1 + c4);
    float4 hq[4];
    #pragma unroll
    for (int r = 0; r < 4; ++r) {
        hq[r].x = lrelu(acc[0][r] + b1q.x);
        hq[r].y = lrelu(acc[1][r] + b1q.y);
        hq[r].z = lrelu(acc[2][r] + b1q.z);
        hq[r].w = lrelu(acc[3][r] + b1q.w);
    }
    __builtin_amdgcn_wave_barrier();
    repack1(Aa, hq, wm, g, c4);        // Aa dead after gemm -> overlay (hi plane only)
    __builtin_amdgcn_wave_barrier();

    f32x4 acc2[4];
    #pragma unroll
    for (int t = 0; t < 4; ++t) acc2[t] = z4;
    gemm64h(Aa, wfW2, rowA, g, lane, acc2);

    const float4 b2q = *reinterpret_cast<const float4*>(b2 + c4);
    const float b2a[4] = {b2q.x, b2q.y, b2q.z, b2q.w};
    #pragma unroll
    for (int t = 0; t < 4; ++t) {
        #pragma unroll
        for (int r = 0; r < 4; ++r) acc2[t][r] = lrelu(acc2[t][r] + b2a[t]);
    }
    const float4 gq = *reinterpret_cast<const float4*>(gam + c4);
    const float4 bq = *reinterpret_cast<const float4*>(bet + c4);
    float4 nq[4];
    #pragma unroll
    for (int r = 0; r < 4; ++r) {
        float s = acc2[0][r] + acc2[1][r] + acc2[2][r] + acc2[3][r];
        s += __shfl_xor(s, 1); s += __shfl_xor(s, 2); s += __shfl_xor(s, 4); s += __shfl_xor(s, 8);
        const float mu = s * 0.015625f;
        float q = 0.f;
        #pragma unroll
        for (int t = 0; t < 4; ++t) { const float d = acc2[t][r] - mu; q = fmaf(d, d, q); }
        q += __shfl_xor(q, 1); q += __shfl_xor(q, 2); q += __shfl_xor(q, 4); q += __shfl_xor(q, 8);
        const float rs = rsqrtf(q * 0.015625f + 1e-5f);
        const int rl = wm * 16 + g * 4 + r;
        const int off = rl * 64 + (((c4 >> 3) ^ (rl & 7)) << 3) + (c4 & 7);
        const short4v nh = *reinterpret_cast<const short4v*>(An + off);
        const short4v nl = *reinterpret_cast<const short4v*>(An + 4096 + off);
        nq[r].x = (acc2[0][r] - mu) * rs * gq.x + bq.x + bf16_to_f((unsigned short)nh[0]) + bf16_to_f((unsigned short)nl[0]);
        nq[r].y = (acc2[1][r] - mu) * rs * gq.y + bq.y + bf16_to_f((unsigned short)nh[1]) + bf16_to_f((unsigned short)nl[1]);
        nq[r].z = (acc2[2][r] - mu) * rs * gq.z + bq.z + bf16_to_f((unsigned short)nh[2]) + bf16_to_f((unsigned short)nl[2]);
        nq[r].w = (acc2[3][r] - mu) * rs * gq.w + bq.w + bf16_to_f((unsigned short)nh[3]) + bf16_to_f((unsigned short)nl[3]);
        const int grow = row0 + rl;
        if (grow < N)
            *reinterpret_cast<float4*>(n + (long long)grow * 64 + c4) = nq[r];
    }

    if (wfB) {
        __builtin_amdgcn_wave_barrier();
        repack1(An, nq, wm, g, c4);    // An residual consumed -> overlay hi plane with n_new
        __builtin_amdgcn_wave_barrier();
        #pragma unroll
        for (int t = 0; t < 4; ++t) acc2[t] = z4;
        gemm64h(An, wfB, rowA, g, lane, acc2);
        #pragma unroll
        for (int r = 0; r < 4; ++r) {
            const int grow = row0 + wm * 16 + g * 4 + r;
            if (grow < N) {
                short4v o;
                o[0] = (short)bf16_rne(acc2[0][r]);
                o[1] = (short)bf16_rne(acc2[1][r]);
                o[2] = (short)bf16_rne(acc2[2][r]);
                o[3] = (short)bf16_rne(acc2[3][r]);
                *reinterpret_cast<short4v*>(u + (long long)grow * 64 + c4) = o;
            }
        }
        #pragma unroll
        for (int t = 0; t < 4; ++t) acc2[t] = z4;
        gemm64h(An, wfC, rowA, g, lane, acc2);
        #pragma unroll
        for (int r = 0; r < 4; ++r) {
            const int grow = row0 + wm * 16 + g * 4 + r;
            if (grow < N) {
                short4v o;
                o[0] = (short)bf16_rne(acc2[0][r]);
                o[1] = (short)bf16_rne(acc2[1][r]);
                o[2] = (short)bf16_rne(acc2[2][r]);
                o[3] = (short)bf16_rne(acc2[3][r]);
                *reinterpret_cast<short4v*>(v + (long long)grow * 64 + c4) = o;
            }
        }
    }
}

// ---------------- decoder: per-wave, shfl-reduce tail (OUT=3) ----------------
__global__ __launch_bounds__(256, 4) void k_dec_mf(
    const float* __restrict__ n, const short* __restrict__ wfW1, const float* __restrict__ b1,
    const float* __restrict__ W2, const float* __restrict__ b2,
    float* __restrict__ out, int N)
{
    __shared__ short An[8192];
    const int row0 = blockIdx.x * 64;
    const int lane = threadIdx.x & 63;
    const int wm = threadIdx.x >> 6;
    const int g = lane >> 4, c = lane & 15;
    const int c4 = c << 2;
    const int rowA = wm * 16 + c;
    stageW(n, row0, N, An, wm, lane);
    __builtin_amdgcn_wave_barrier();
    const f32x4 z4 = {0.f, 0.f, 0.f, 0.f};
    f32x4 acc[4];
    #pragma unroll
    for (int t = 0; t < 4; ++t) acc[t] = z4;
    gemm64(An, wfW1, rowA, g, lane, acc);
    const float4 b1q = *reinterpret_cast<const float4*>(b1 + c4);
    const float b1a[4] = {b1q.x, b1q.y, b1q.z, b1q.w};
    #pragma unroll
    for (int t = 0; t < 4; ++t)
        #pragma unroll
        for (int r = 0; r < 4; ++r) acc[t][r] = lrelu(acc[t][r] + b1a[t]);
    const float4 w0 = *reinterpret_cast<const float4*>(W2 + c4 * 3);
    const float4 w1 = *reinterpret_cast<const float4*>(W2 + c4 * 3 + 4);
    const float4 w2 = *reinterpret_cast<const float4*>(W2 + c4 * 3 + 8);
    const float wv[12] = {w0.x,w0.y,w0.z,w0.w, w1.x,w1.y,w1.z,w1.w, w2.x,w2.y,w2.z,w2.w};
    float po[4][3];
    #pragma unroll
    for (int r = 0; r < 4; ++r)
        #pragma unroll
        for (int o = 0; o < 3; ++o)
            po[r][o] = acc[0][r]*wv[o] + acc[1][r]*wv[3+o] + acc[2][r]*wv[6+o] + acc[3][r]*wv[9+o];
    #pragma unroll
    for (int m = 1; m <= 8; m <<= 1)
        #pragma unroll
        for (int r = 0; r < 4; ++r)
            #pragma unroll
            for (int o = 0; o < 3; ++o)
                po[r][o] += __shfl_xor(po[r][o], m);
    if (c < 3) {
        #pragma unroll
        for (int r = 0; r < 4; ++r) {
            const int grow = row0 + wm * 16 + g * 4 + r;
            const float val = (c == 0) ? po[r][0] : (c == 1) ? po[r][1] : po[r][2];
            if (grow < N) out[(long long)grow * 3 + c] = b2[c] + val;
        }
    }
}

// ================= CSR build =================
__global__ void k_hist(const int* __restrict__ eidx, int* __restrict__ cnt, int E)
{
    int i = blockIdx.x * 256 + threadIdx.x;
    if (i < E) atomicAdd(&cnt[eidx[2 * i]], 1);
}

__global__ void k_scan1(const int* __restrict__ cnt, int* __restrict__ starts,
                        int* __restrict__ bsum, int n)
{
    __shared__ int sh[256];
    const int tid = threadIdx.x;
    const int i = blockIdx.x * 256 + tid;
    const int val = (i < n) ? cnt[i] : 0;
    sh[tid] = val; __syncthreads();
    for (int off = 1; off < 256; off <<= 1) {
        int t = (tid >= off) ? sh[tid - off] : 0;
        __syncthreads();
        sh[tid] += t;
        __syncthreads();
    }
    if (i < n) starts[i] = sh[tid] - val;
    if (tid == 255) bsum[blockIdx.x] = sh[255];
}

__global__ void k_scan2(int* __restrict__ bsum, int nb)
{
    __shared__ int sh[256];
    const int tid = threadIdx.x;
    const int val = (tid < nb) ? bsum[tid] : 0;
    sh[tid] = val; __syncthreads();
    for (int off = 1; off < 256; off <<= 1) {
        int t = (tid >= off) ? sh[tid - off] : 0;
        __syncthreads();
        sh[tid] += t;
        __syncthreads();
    }
    if (tid < nb) bsum[tid] = sh[tid] - val;
}

__global__ void k_scan3(int* __restrict__ starts, const int* __restrict__ bsum, int n)
{
    int i = blockIdx.x * 256 + threadIdx.x;
    if (i < n) starts[i] += bsum[blockIdx.x];
}

__global__ void k_scatter(const int* __restrict__ eidx, const int* __restrict__ starts,
                          int* __restrict__ cursor, int* __restrict__ csr,
                          int* __restrict__ sp, int* __restrict__ rp, int E)
{
    int i = blockIdx.x * 256 + threadIdx.x;
    if (i < E) {
        const int s = eidx[2 * i];
        const int p = atomicAdd(&cursor[s], 1);
        const int q = starts[s] + p;
        csr[q] = i;
        sp[q] = s;
        rp[q] = eidx[2 * i + 1];
    }
}

extern "C" void kernel_launch(void* const* d_in, const int* in_sizes, int n_in,
                              void* d_out, int out_size, void* d_ws, size_t ws_size,
                              hipStream_t stream)
{
    (void)in_sizes; (void)n_in; (void)out_size; (void)ws_size;
    constexpr int N = 50000, E = 300000, L = 3;

    const float* nodes = (const float*)d_in[0];
    const float* edges = (const float*)d_in[1];
    const int*   eidx  = (const int*)d_in[2];
    const float* neW1 = (const float*)d_in[3];
    const float* neb1 = (const float*)d_in[4];
    const float* neW2 = (const float*)d_in[5];
    const float* neb2 = (const float*)d_in[6];
    const float* neg  = (const float*)d_in[7];
    const float* nebe = (const float*)d_in[8];
    const float* eeW1 = (const float*)d_in[9];
    const float* eeb1 = (const float*)d_in[10];
    const float* eeW2 = (const float*)d_in[11];
    const float* eeb2 = (const float*)d_in[12];
    const float* eeg  = (const float*)d_in[13];
    const float* eebe = (const float*)d_in[14];
    const float* nmW1 = (const float*)d_in[15];
    const float* nmb1 = (const float*)d_in[16];
    const float* nmW2 = (const float*)d_in[17];
    const float* nmb2 = (const float*)d_in[18];
    const float* nmg  = (const float*)d_in[19];
    const float* nmbe = (const float*)d_in[20];
    const float* emW1 = (const float*)d_in[21];
    const float* emb1 = (const float*)d_in[22];
    const float* emW2 = (const float*)d_in[23];
    const float* emb2 = (const float*)d_in[24];
    const float* emg  = (const float*)d_in[25];
    const float* embe = (const float*)d_in[26];
    const float* decW1 = (const float*)d_in[27];
    const float* decb1 = (const float*)d_in[28];
    const float* decW2 = (const float*)d_in[29];
    const float* decb2 = (const float*)d_in[30];

    // workspace: n(f32) | aggr(f32) | ubf | vbf | ints | wf | ebf
    float* n    = (float*)d_ws;                       // N*64 f32
    float* aggr = n + (size_t)N * 64;                 // N*64 f32
    unsigned short* ubf = (unsigned short*)(aggr + (size_t)N * 64);  // N*64 bf16
    unsigned short* vbf = ubf + (size_t)N * 64;       // N*64 bf16
    int* cnt    = (int*)(vbf + (size_t)N * 64);       // N
    int* starts = cnt + N;                            // N
    int* csr    = starts + N;                         // E
    int* bsum   = csr + E;                            // 256
    int* cursor = bsum + 256;                         // N
    int* sp     = cursor + N;                         // E
    int* rp     = sp + E;                             // E
    short* wf   = (short*)(rp + E);                   // 24 * 8192 shorts
    unsigned short* ebf = (unsigned short*)(wf + (size_t)24 * 8192);  // E*64 bf16

    const int nbN = (N + 255) / 256;
    const int nbE = (E + 255) / 256;
    const int nbN64 = (N + 63) / 64;            // 782
    const int nbE64 = (E + 63) / 64;            // 4688

    const short* wfEE  = wf + (size_t)21 * 8192;
    const short* wfNE  = wf + (size_t)22 * 8192;
    const short* wfDec = wf + (size_t)23 * 8192;

    // ---- weight fragment prep + CSR build ----
    k_prepw<<<24, 256, 0, stream>>>(emW1, emW2, nmW1, nmW2, eeW2, neW2, decW1, wf);
    hipMemsetAsync(cnt, 0, (size_t)N * sizeof(int), stream);
    hipMemsetAsync(cursor, 0, (size_t)N * sizeof(int), stream);
    k_hist<<<nbE, 256, 0, stream>>>(eidx, cnt, E);
    k_scan1<<<nbN, 256, 0, stream>>>(cnt, starts, bsum, N);
    k_scan2<<<1, 256, 0, stream>>>(bsum, nbN);
    k_scan3<<<nbN, 256, 0, stream>>>(starts, bsum, N);
    k_scatter<<<nbE, 256, 0, stream>>>(eidx, starts, cursor, csr, sp, rp, E);

    // ---- encode (node encoder also emits u,v for layer 0; edge encoder writes bf16 e) ----
    const short* wl0 = wf;
    k_enc_mf<16, false, true, false><<<nbN64, 256, 0, stream>>>(
        nodes, nullptr, neW1, neb1, wfNE, neb2, neg, nebe, n,
        wl0 + 8192, wl0 + 2 * 8192, ubf, vbf, N);
    k_enc_mf<8, true, false, true><<<nbE64, 256, 0, stream>>>(
        edges, csr, eeW1, eeb1, wfEE, eeb2, eeg, eebe, (float*)ebf,
        nullptr, nullptr, nullptr, nullptr, E);

    // ---- message-passing layers ----
    for (int i = 0; i < L; ++i) {
        const short* wl = wf + (size_t)i * 7 * 8192;
        k_edge_mf<<<nbE64, 256, 0, stream>>>(ebf, sp, rp, ubf, vbf, wl, wl + 3 * 8192,
                                             emb1 + i * 64, emb2 + i * 64,
                                             emg + i * 64, embe + i * 64, E);
        k_aggr<<<(N + 3) / 4, 256, 0, stream>>>(ebf, starts, cnt, aggr, N);
        const short* wln = (i + 1 < L) ? wf + (size_t)(i + 1) * 7 * 8192 : nullptr;
        k_node_mf<<<nbN64, 256, 0, stream>>>(n, aggr,
                                             wl + 4 * 8192, wl + 5 * 8192, wl + 6 * 8192,
                                             nmb1 + i * 64, nmb2 + i * 64,
                                             nmg + i * 64, nmbe + i * 64,
                                             wln ? wln + 8192 : nullptr,
                                             wln ? wln + 2 * 8192 : nullptr,
                                             ubf, vbf, N);
    }
    k_dec_mf<<<nbN64, 256, 0, stream>>>(n, wfDec, decb1, decW2, decb2, (float*)d_out, N);
}

// Round 15
// 400.370 us; speedup vs baseline: 1.1608x; 1.0371x over previous
//
#include <hip/hip_runtime.h>

typedef __attribute__((ext_vector_type(8))) short short8v;
typedef __attribute__((ext_vector_type(4))) short short4v;
typedef __attribute__((ext_vector_type(4))) float f32x4;

__device__ __forceinline__ float lrelu(float x) { return x >= 0.f ? x : 0.05f * x; }

__device__ __forceinline__ unsigned short bf16_rne(float x) {
    unsigned u = __float_as_uint(x);
    u += 0x7FFFu + ((u >> 16) & 1u);
    return (unsigned short)(u >> 16);
}
__device__ __forceinline__ float bf16_to_f(unsigned short h) {
    return __uint_as_float(((unsigned)h) << 16);
}
__device__ __forceinline__ void split2(float x, unsigned short& hi, unsigned short& lo) {
    hi = bf16_rne(x);
    lo = bf16_rne(x - bf16_to_f(hi));
}

// ================= MFMA machinery =================
// A-frag (M=16,K=32): lane holds A[row=lane&15][k=(lane>>4)*8+i]
// B-frag: lane holds B[k][frag col16=lane&15]; COLUMN INTERLEAVE: frag t, col16 c -> global col 4c+t.
// C/D: col16=lane&15, row=(lane>>4)*4+reg
// LDS A layout per plane: A[row][k] shorts, 16B slots XOR-swizzled: slot=(k>>3)^(row&7); lo plane at +4096.
// Precision: weights hi/lo; staged fp32 tensors (n, aggr) hi/lo; e/u/v global bf16;
// hidden activations H single bf16.
// MEASURED-BEST CONFIG (round 12, 401 us): all MLP kernels at launch_bounds(256,4).
// Lessons locked in: no in-thread multi-tile pipelining (rounds 9/10: regalloc spills);
// no higher min-waves launch_bounds (rounds 13/14: VGPR clamp -> spills).

__device__ __forceinline__ void stageW(const float* src, int row0, int nrows,
                                       short* __restrict__ A, int wm, int lane)
{
    #pragma unroll
    for (int it = 0; it < 4; ++it) {
        const int q = it * 64 + lane;
        const int rl = wm * 16 + (q >> 4);
        const int k0 = (q & 15) << 2;
        const int grow = row0 + rl;
        float4 x = (grow < nrows) ? *reinterpret_cast<const float4*>(src + (long long)grow * 64 + k0)
                                  : make_float4(0.f, 0.f, 0.f, 0.f);
        unsigned short h0,h1,h2,h3,l0,l1,l2,l3;
        split2(x.x, h0, l0); split2(x.y, h1, l1); split2(x.z, h2, l2); split2(x.w, h3, l3);
        const int off = rl * 64 + ((((k0 >> 3) ^ (rl & 7))) << 3) + (k0 & 7);
        short4v hv; hv[0]=(short)h0; hv[1]=(short)h1; hv[2]=(short)h2; hv[3]=(short)h3;
        short4v lv; lv[0]=(short)l0; lv[1]=(short)l1; lv[2]=(short)l2; lv[3]=(short)l3;
        *reinterpret_cast<short4v*>(A + off) = hv;
        *reinterpret_cast<short4v*>(A + 4096 + off) = lv;
    }
}

__device__ __forceinline__ void gemm64(const short* __restrict__ A, const short* __restrict__ wf,
                                       int row, int g, int lane, f32x4* __restrict__ acc)
{
    #pragma unroll
    for (int s = 0; s < 2; ++s) {
        const int k8 = s * 4 + g;
        const int aoff = row * 64 + ((k8 ^ (row & 7)) << 3);
        const short8v a_hi = *reinterpret_cast<const short8v*>(A + aoff);
        const short8v a_lo = *reinterpret_cast<const short8v*>(A + 4096 + aoff);
        #pragma unroll
        for (int t = 0; t < 4; ++t) {
            const short8v b_hi = *reinterpret_cast<const short8v*>(wf + ((s*4+t)*2+0)*512 + lane*8);
            const short8v b_lo = *reinterpret_cast<const short8v*>(wf + ((s*4+t)*2+1)*512 + lane*8);
            acc[t] = __builtin_amdgcn_mfma_f32_16x16x32_bf16(a_hi, b_hi, acc[t], 0, 0, 0);
            acc[t] = __builtin_amdgcn_mfma_f32_16x16x32_bf16(a_lo, b_hi, acc[t], 0, 0, 0);
            acc[t] = __builtin_amdgcn_mfma_f32_16x16x32_bf16(a_hi, b_lo, acc[t], 0, 0, 0);
        }
    }
}

__device__ __forceinline__ void gemm64h(const short* __restrict__ A, const short* __restrict__ wf,
                                        int row, int g, int lane, f32x4* __restrict__ acc)
{
    #pragma unroll
    for (int s = 0; s < 2; ++s) {
        const int k8 = s * 4 + g;
        const int aoff = row * 64 + ((k8 ^ (row & 7)) << 3);
        const short8v a = *reinterpret_cast<const short8v*>(A + aoff);
        #pragma unroll
        for (int t = 0; t < 4; ++t) {
            const short8v b_hi = *reinterpret_cast<const short8v*>(wf + ((s*4+t)*2+0)*512 + lane*8);
            const short8v b_lo = *reinterpret_cast<const short8v*>(wf + ((s*4+t)*2+1)*512 + lane*8);
            acc[t] = __builtin_amdgcn_mfma_f32_16x16x32_bf16(a, b_hi, acc[t], 0, 0, 0);
            acc[t] = __builtin_amdgcn_mfma_f32_16x16x32_bf16(a, b_lo, acc[t], 0, 0, 0);
        }
    }
}

__device__ __forceinline__ void repack1(short* __restrict__ A, const float4* __restrict__ q,
                                        int wm, int g, int c4)
{
    #pragma unroll
    for (int r = 0; r < 4; ++r) {
        const int rl = wm * 16 + g * 4 + r;
        const int off = rl * 64 + (((c4 >> 3) ^ (rl & 7)) << 3) + (c4 & 7);
        short4v hv;
        hv[0] = (short)bf16_rne(q[r].x);
        hv[1] = (short)bf16_rne(q[r].y);
        hv[2] = (short)bf16_rne(q[r].z);
        hv[3] = (short)bf16_rne(q[r].w);
        *reinterpret_cast<short4v*>(A + off) = hv;
    }
}

// Preformat 64x64 fp32 W[k][col] chunks -> hi/lo B-fragments (interleaved col map).
__global__ void k_prepw(const float* __restrict__ emW1, const float* __restrict__ emW2,
                        const float* __restrict__ nmW1, const float* __restrict__ nmW2,
                        const float* __restrict__ eeW2, const float* __restrict__ neW2,
                        const float* __restrict__ decW1,
                        short* __restrict__ wf)
{
    const int cid = blockIdx.x;
    const float* src;
    if (cid < 21) {
        const int layer = cid / 7, j = cid % 7;
        src =
            j == 0 ? emW1 + (size_t)layer * 12288 :
            j == 1 ? emW1 + (size_t)layer * 12288 + 4096 :
            j == 2 ? emW1 + (size_t)layer * 12288 + 8192 :
            j == 3 ? emW2 + (size_t)layer * 4096 :
            j == 4 ? nmW1 + (size_t)layer * 8192 :
            j == 5 ? nmW1 + (size_t)layer * 8192 + 4096 :
                     nmW2 + (size_t)layer * 4096;
    } else {
        src = (cid == 21) ? eeW2 : (cid == 22) ? neW2 : decW1;
    }
    short* dst = wf + (size_t)cid * 8192;
    for (int fr = threadIdx.x; fr < 1024; fr += 256) {
        const int lane = fr & 63;
        const int stp = fr >> 6;
        const int p = stp & 1;
        const int st = stp >> 1;
        const int s = st >> 2, t = st & 3;
        const int col = ((lane & 15) << 2) + t;
        const int k0 = s * 32 + (lane >> 4) * 8;
        short8v o;
        #pragma unroll
        for (int i = 0; i < 8; ++i) {
            const float w = src[(k0 + i) * 64 + col];
            const unsigned short hi = bf16_rne(w);
            o[i] = (short)(p ? bf16_rne(w - bf16_to_f(hi)) : hi);
        }
        *reinterpret_cast<short8v*>(dst + fr * 8) = o;
    }
}

// ---------------- encoder; MAKEUV: also emit u,v (bf16); OUTBF16: bf16 output (edge stream) ----------------
template<int DIN, bool PERM, bool MAKEUV, bool OUTBF16>
__global__ __launch_bounds__(256, 4) void k_enc_mf(
    const float* __restrict__ x, const int* __restrict__ csr,
    const float* __restrict__ W1, const float* __restrict__ b1,
    const short* __restrict__ wfW2, const float* __restrict__ b2,
    const float* __restrict__ gam, const float* __restrict__ bet,
    float* __restrict__ out,
    const short* __restrict__ wfB, const short* __restrict__ wfC,
    unsigned short* __restrict__ u, unsigned short* __restrict__ v, int nrows)
{
    __shared__ short Hf[4096];
    const int row0 = blockIdx.x * 64;
    const int lane = threadIdx.x & 63;
    const int wm = threadIdx.x >> 6;
    const int g = lane >> 4, c = lane & 15;
    const int c4 = c << 2;
    const int rowA = wm * 16 + c;

    long long orig[4];
    #pragma unroll
    for (int r = 0; r < 4; ++r) {
        const int grow = row0 + wm * 16 + g * 4 + r;
        orig[r] = (grow < nrows) ? (long long)(PERM ? csr[grow] : grow) : -1;
    }

    const f32x4 z4 = {0.f, 0.f, 0.f, 0.f};
    f32x4 acc[4];
    #pragma unroll
    for (int t = 0; t < 4; ++t) acc[t] = z4;

    #pragma unroll
    for (int kq = 0; kq < DIN / 4; ++kq) {
        float xv[4][4];
        #pragma unroll
        for (int r = 0; r < 4; ++r) {
            float4 t4 = make_float4(0.f, 0.f, 0.f, 0.f);
            if (orig[r] >= 0)
                t4 = *reinterpret_cast<const float4*>(x + orig[r] * DIN + kq * 4);
            xv[r][0] = t4.x; xv[r][1] = t4.y; xv[r][2] = t4.z; xv[r][3] = t4.w;
        }
        #pragma unroll
        for (int i = 0; i < 4; ++i) {
            const int k = kq * 4 + i;
            const float4 w4 = *reinterpret_cast<const float4*>(W1 + k * 64 + c4);
            const float wv[4] = {w4.x, w4.y, w4.z, w4.w};
            #pragma unroll
            for (int t = 0; t < 4; ++t)
                #pragma unroll
                for (int r = 0; r < 4; ++r)
                    acc[t][r] = fmaf(xv[r][i], wv[t], acc[t][r]);
        }
    }

    const float4 b1q = *reinterpret_cast<const float4*>(b1 + c4);
    float4 hq[4];
    #pragma unroll
    for (int r = 0; r < 4; ++r) {
        hq[r].x = lrelu(acc[0][r] + b1q.x);
        hq[r].y = lrelu(acc[1][r] + b1q.y);
        hq[r].z = lrelu(acc[2][r] + b1q.z);
        hq[r].w = lrelu(acc[3][r] + b1q.w);
    }
    repack1(Hf, hq, wm, g, c4);
    __builtin_amdgcn_wave_barrier();

    f32x4 acc2[4];
    #pragma unroll
    for (int t = 0; t < 4; ++t) acc2[t] = z4;
    gemm64h(Hf, wfW2, rowA, g, lane, acc2);

    const float4 b2q = *reinterpret_cast<const float4*>(b2 + c4);
    const float b2a[4] = {b2q.x, b2q.y, b2q.z, b2q.w};
    #pragma unroll
    for (int t = 0; t < 4; ++t) {
        #pragma unroll
        for (int r = 0; r < 4; ++r) acc2[t][r] = lrelu(acc2[t][r] + b2a[t]);
    }
    const float4 gq = *reinterpret_cast<const float4*>(gam + c4);
    const float4 bq = *reinterpret_cast<const float4*>(bet + c4);
    float4 nq[4];
    #pragma unroll
    for (int r = 0; r < 4; ++r) {
        float s = acc2[0][r] + acc2[1][r] + acc2[2][r] + acc2[3][r];
        s += __shfl_xor(s, 1); s += __shfl_xor(s, 2); s += __shfl_xor(s, 4); s += __shfl_xor(s, 8);
        const float mu = s * 0.015625f;
        float q = 0.f;
        #pragma unroll
        for (int t = 0; t < 4; ++t) { const float d = acc2[t][r] - mu; q = fmaf(d, d, q); }
        q += __shfl_xor(q, 1); q += __shfl_xor(q, 2); q += __shfl_xor(q, 4); q += __shfl_xor(q, 8);
        const float rs = rsqrtf(q * 0.015625f + 1e-5f);
        nq[r].x = (acc2[0][r] - mu) * rs * gq.x + bq.x;
        nq[r].y = (acc2[1][r] - mu) * rs * gq.y + bq.y;
        nq[r].z = (acc2[2][r] - mu) * rs * gq.z + bq.z;
        nq[r].w = (acc2[3][r] - mu) * rs * gq.w + bq.w;
        const int grow = row0 + wm * 16 + g * 4 + r;
        if (grow < nrows) {
            if constexpr (OUTBF16) {
                short4v st;
                st[0] = (short)bf16_rne(nq[r].x);
                st[1] = (short)bf16_rne(nq[r].y);
                st[2] = (short)bf16_rne(nq[r].z);
                st[3] = (short)bf16_rne(nq[r].w);
                *reinterpret_cast<short4v*>(reinterpret_cast<unsigned short*>(out) + (long long)grow * 64 + c4) = st;
            } else {
                *reinterpret_cast<float4*>(out + (long long)grow * 64 + c4) = nq[r];
            }
        }
    }

    if constexpr (MAKEUV) {
        __builtin_amdgcn_wave_barrier();
        repack1(Hf, nq, wm, g, c4);
        __builtin_amdgcn_wave_barrier();
        #pragma unroll
        for (int t = 0; t < 4; ++t) acc2[t] = z4;
        gemm64h(Hf, wfB, rowA, g, lane, acc2);
        #pragma unroll
        for (int r = 0; r < 4; ++r) {
            const int grow = row0 + wm * 16 + g * 4 + r;
            if (grow < nrows) {
                short4v o;
                o[0] = (short)bf16_rne(acc2[0][r]);
                o[1] = (short)bf16_rne(acc2[1][r]);
                o[2] = (short)bf16_rne(acc2[2][r]);
                o[3] = (short)bf16_rne(acc2[3][r]);
                *reinterpret_cast<short4v*>(u + (long long)grow * 64 + c4) = o;
            }
        }
        #pragma unroll
        for (int t = 0; t < 4; ++t) acc2[t] = z4;
        gemm64h(Hf, wfC, rowA, g, lane, acc2);
        #pragma unroll
        for (int r = 0; r < 4; ++r) {
            const int grow = row0 + wm * 16 + g * 4 + r;
            if (grow < nrows) {
                short4v o;
                o[0] = (short)bf16_rne(acc2[0][r]);
                o[1] = (short)bf16_rne(acc2[1][r]);
                o[2] = (short)bf16_rne(acc2[2][r]);
                o[3] = (short)bf16_rne(acc2[3][r]);
                *reinterpret_cast<short4v*>(v + (long long)grow * 64 + c4) = o;
            }
        }
    }
}

// ---------------- edge update: e(bf16) += LN(lrelu(lrelu(e@A + u[s] + v[r] + b1)@W2 + b2)) ----
__global__ __launch_bounds__(256, 4) void k_edge_mf(
    unsigned short* ebf, const int* __restrict__ sp, const int* __restrict__ rp,
    const unsigned short* __restrict__ u, const unsigned short* __restrict__ v,
    const short* __restrict__ wfA, const short* __restrict__ wfW2,
    const float* __restrict__ b1, const float* __restrict__ b2,
    const float* __restrict__ gam, const float* __restrict__ bet, int E)
{
    __shared__ short Hf[4096];
    const int row0 = blockIdx.x * 64;
    const int lane = threadIdx.x & 63;
    const int wm = threadIdx.x >> 6;
    const int g = lane >> 4, c = lane & 15;
    const int c4 = c << 2;
    const int rowA = wm * 16 + c;

    int sidx[4], ridx[4];
    #pragma unroll
    for (int r = 0; r < 4; ++r) {
        const int grow = row0 + wm * 16 + g * 4 + r;
        if (grow < E) { sidx[r] = sp[grow]; ridx[r] = rp[grow]; }
        else          { sidx[r] = 0; ridx[r] = 0; }
    }
    const int arow = (row0 + rowA < E) ? row0 + rowA : 0;
    const short8v a0 = *reinterpret_cast<const short8v*>(ebf + (long long)arow * 64 + g * 8);
    const short8v a1 = *reinterpret_cast<const short8v*>(ebf + (long long)arow * 64 + 32 + g * 8);
    short4v eold[4];
    #pragma unroll
    for (int r = 0; r < 4; ++r) {
        const int grow = row0 + wm * 16 + g * 4 + r;
        const int rc = (grow < E) ? grow : 0;
        eold[r] = *reinterpret_cast<const short4v*>(ebf + (long long)rc * 64 + c4);
    }
    short4v us[4], vs[4];
    #pragma unroll
    for (int r = 0; r < 4; ++r) {
        us[r] = *reinterpret_cast<const short4v*>(u + (long long)sidx[r] * 64 + c4);
        vs[r] = *reinterpret_cast<const short4v*>(v + (long long)ridx[r] * 64 + c4);
    }

    const f32x4 z4 = {0.f, 0.f, 0.f, 0.f};
    f32x4 acc[4];
    #pragma unroll
    for (int t = 0; t < 4; ++t) acc[t] = z4;
    #pragma unroll
    for (int s = 0; s < 2; ++s) {
        const short8v a = s ? a1 : a0;
        #pragma unroll
        for (int t = 0; t < 4; ++t) {
            const short8v b_hi = *reinterpret_cast<const short8v*>(wfA + ((s*4+t)*2+0)*512 + lane*8);
            const short8v b_lo = *reinterpret_cast<const short8v*>(wfA + ((s*4+t)*2+1)*512 + lane*8);
            acc[t] = __builtin_amdgcn_mfma_f32_16x16x32_bf16(a, b_hi, acc[t], 0, 0, 0);
            acc[t] = __builtin_amdgcn_mfma_f32_16x16x32_bf16(a, b_lo, acc[t], 0, 0, 0);
        }
    }

    const float4 b1q = *reinterpret_cast<const float4*>(b1 + c4);
    float4 hq[4];
    #pragma unroll
    for (int r = 0; r < 4; ++r) {
        hq[r].x = lrelu(acc[0][r] + b1q.x + bf16_to_f((unsigned short)us[r][0]) + bf16_to_f((unsigned short)vs[r][0]));
        hq[r].y = lrelu(acc[1][r] + b1q.y + bf16_to_f((unsigned short)us[r][1]) + bf16_to_f((unsigned short)vs[r][1]));
        hq[r].z = lrelu(acc[2][r] + b1q.z + bf16_to_f((unsigned short)us[r][2]) + bf16_to_f((unsigned short)vs[r][2]));
        hq[r].w = lrelu(acc[3][r] + b1q.w + bf16_to_f((unsigned short)us[r][3]) + bf16_to_f((unsigned short)vs[r][3]));
    }
    repack1(Hf, hq, wm, g, c4);
    __builtin_amdgcn_wave_barrier();

    f32x4 acc2[4];
    #pragma unroll
    for (int t = 0; t < 4; ++t) acc2[t] = z4;
    gemm64h(Hf, wfW2, rowA, g, lane, acc2);

    const float4 b2q = *reinterpret_cast<const float4*>(b2 + c4);
    const float b2a[4] = {b2q.x, b2q.y, b2q.z, b2q.w};
    #pragma unroll
    for (int t = 0; t < 4; ++t) {
        #pragma unroll
        for (int r = 0; r < 4; ++r) acc2[t][r] = lrelu(acc2[t][r] + b2a[t]);
    }
    const float4 gq = *reinterpret_cast<const float4*>(gam + c4);
    const float4 bq = *reinterpret_cast<const float4*>(bet + c4);
    #pragma unroll
    for (int r = 0; r < 4; ++r) {
        float s = acc2[0][r] + acc2[1][r] + acc2[2][r] + acc2[3][r];
        s += __shfl_xor(s, 1); s += __shfl_xor(s, 2); s += __shfl_xor(s, 4); s += __shfl_xor(s, 8);
        const float mu = s * 0.015625f;
        float q = 0.f;
        #pragma unroll
        for (int t = 0; t < 4; ++t) { const float d = acc2[t][r] - mu; q = fmaf(d, d, q); }
        q += __shfl_xor(q, 1); q += __shfl_xor(q, 2); q += __shfl_xor(q, 4); q += __shfl_xor(q, 8);
        const float rs = rsqrtf(q * 0.015625f + 1e-5f);
        const int grow = row0 + wm * 16 + g * 4 + r;
        if (grow < E) {
            float ox = (acc2[0][r] - mu) * rs * gq.x + bq.x + bf16_to_f((unsigned short)eold[r][0]);
            float oy = (acc2[1][r] - mu) * rs * gq.y + bq.y + bf16_to_f((unsigned short)eold[r][1]);
            float oz = (acc2[2][r] - mu) * rs * gq.z + bq.z + bf16_to_f((unsigned short)eold[r][2]);
            float ow = (acc2[3][r] - mu) * rs * gq.w + bq.w + bf16_to_f((unsigned short)eold[r][3]);
            short4v st;
            st[0] = (short)bf16_rne(ox);
            st[1] = (short)bf16_rne(oy);
            st[2] = (short)bf16_rne(oz);
            st[3] = (short)bf16_rne(ow);
            *reinterpret_cast<short4v*>(ebf + (long long)grow * 64 + c4) = st;
        }
    }
}

// ---------------- aggregation: wave per node, lane = column, coalesced bf16 CSR scan ----------------
__global__ __launch_bounds__(256) void k_aggr(
    const unsigned short* __restrict__ ebf, const int* __restrict__ starts,
    const int* __restrict__ cnt, float* __restrict__ aggr, int N)
{
    const int node = blockIdx.x * 4 + (threadIdx.x >> 6);
    if (node >= N) return;
    const int j = threadIdx.x & 63;
    const int st = starts[node], en = st + cnt[node];
    float a = 0.f;
    for (int t = st; t < en; ++t)
        a += bf16_to_f(ebf[(long long)t * 64 + j]);
    aggr[(long long)node * 64 + j] = a;
}

// ---------------- node update: n += MLP(concat[n, aggr]); fused uv (bf16) for next layer ----------------
__global__ __launch_bounds__(256, 4) void k_node_mf(
    float* n, const float* aggr,
    const short* __restrict__ wfW1a, const short* __restrict__ wfW1b, const short* __restrict__ wfW2,
    const float* __restrict__ b1, const float* __restrict__ b2,
    const float* __restrict__ gam, const float* __restrict__ bet,
    const short* __restrict__ wfB, const short* __restrict__ wfC,
    unsigned short* __restrict__ u, unsigned short* __restrict__ v, int N)
{
    __shared__ short An[8192];
    __shared__ short Aa[8192];
    const int row0 = blockIdx.x * 64;
    const int lane = threadIdx.x & 63;
    const int wm = threadIdx.x >> 6;
    const int g = lane >> 4, c = lane & 15;
    const int c4 = c << 2;
    const int rowA = wm * 16 + c;

    stageW(n, row0, N, An, wm, lane);
    stageW(aggr, row0, N, Aa, wm, lane);
    __builtin_amdgcn_wave_barrier();

    const f32x4 z4 = {0.f, 0.f, 0.f, 0.f};
    f32x4 acc[4];
    #pragma unroll
    for (int t = 0; t < 4; ++t) acc[t] = z4;
    gemm64(An, wfW1a, rowA, g, lane, acc);
    gemm64(Aa, wfW1b, rowA, g, lane, acc);

    const float4 b1q = *reinterpret_cast<const float4*>(b1 + c4);
    float4 hq[4];
    #pragma unroll
    for (int r = 0; r < 4; ++r) {
        hq[r].x = lrelu(acc[0][r] + b1q.x);
        hq[r].y = lrelu(acc[1][r] + b1q.y);
        hq[r].z = lrelu(acc[2][r] + b1q.z);
        hq[r].w = lrelu(acc[3][r] + b1q.w);
    }
    __builtin_amdgcn_wave_barrier();
    repack1(Aa, hq, wm, g, c4);        // Aa dead after gemm -> overlay (hi plane only)
    __builtin_amdgcn_wave_barrier();

    f32x4 acc2[4];
    #pragma unroll
    for (int t = 0; t < 4; ++t) acc2[t] = z4;
    gemm64h(Aa, wfW2, rowA, g, lane, acc2);

    const float4 b2q = *reinterpret_cast<const float4*>(b2 + c4);
    const float b2a[4] = {b2q.x, b2q.y, b2q.z, b2q.w};
    #pragma unroll
    for (int t = 0; t < 4; ++t) {
        #pragma unroll
        for (int r = 0; r < 4; ++r) acc2[t][r] = lrelu(acc2[t][r] + b2a[t]);
    }
    const float4 gq = *reinterpret_cast<const float4*>(gam + c4);
    const float4 bq = *reinterpret_cast<const float4*>(bet + c4);
    float4 nq[4];
    #pragma unroll
    for (int r = 0; r < 4; ++r) {
        float s = acc2[0][r] + acc2[1][r] + acc2[2][r] + acc2[3][r];
        s += __shfl_xor(s, 1); s += __shfl_xor(s, 2); s += __shfl_xor(s, 4); s += __shfl_xor(s, 8);
        const float mu = s * 0.015625f;
        float q = 0.f;
        #pragma unroll
        for (int t = 0; t < 4; ++t) { const float d = acc2[t][r] - mu; q = fmaf(d, d, q); }
        q += __shfl_xor(q, 1); q += __shfl_xor(q, 2); q += __shfl_xor(q, 4); q += __shfl_xor(q, 8);
        const float rs = rsqrtf(q * 0.015625f + 1e-5f);
        const int rl = wm * 16 + g * 4 + r;
        const int off = rl * 64 + (((c4 >> 3) ^ (rl & 7)) << 3) + (c4 & 7);
        const short4v nh = *reinterpret_cast<const short4v*>(An + off);
        const short4v nl = *reinterpret_cast<const short4v*>(An + 4096 + off);
        nq[r].x = (acc2[0][r] - mu) * rs * gq.x + bq.x + bf16_to_f((unsigned short)nh[0]) + bf16_to_f((unsigned short)nl[0]);
        nq[r].y = (acc2[1][r] - mu) * rs * gq.y + bq.y + bf16_to_f((unsigned short)nh[1]) + bf16_to_f((unsigned short)nl[1]);
        nq[r].z = (acc2[2][r] - mu) * rs * gq.z + bq.z + bf16_to_f((unsigned short)nh[2]) + bf16_to_f((unsigned short)nl[2]);
        nq[r].w = (acc2[3][r] - mu) * rs * gq.w + bq.w + bf16_to_f((unsigned short)nh[3]) + bf16_to_f((unsigned short)nl[3]);
        const int grow = row0 + rl;
        if (grow < N)
            *reinterpret_cast<float4*>(n + (long long)grow * 64 + c4) = nq[r];
    }

    if (wfB) {
        __builtin_amdgcn_wave_barrier();
        repack1(An, nq, wm, g, c4);    // An residual consumed -> overlay hi plane with n_new
        __builtin_amdgcn_wave_barrier();
        #pragma unroll
        for (int t = 0; t < 4; ++t) acc2[t] = z4;
        gemm64h(An, wfB, rowA, g, lane, acc2);
        #pragma unroll
        for (int r = 0; r < 4; ++r) {
            const int grow = row0 + wm * 16 + g * 4 + r;
            if (grow < N) {
                short4v o;
                o[0] = (short)bf16_rne(acc2[0][r]);
                o[1] = (short)bf16_rne(acc2[1][r]);
                o[2] = (short)bf16_rne(acc2[2][r]);
                o[3] = (short)bf16_rne(acc2[3][r]);
                *reinterpret_cast<short4v*>(u + (long long)grow * 64 + c4) = o;
            }
        }
        #pragma unroll
        for (int t = 0; t < 4; ++t) acc2[t] = z4;
        gemm64h(An, wfC, rowA, g, lane, acc2);
        #pragma unroll
        for (int r = 0; r < 4; ++r) {
            const int grow = row0 + wm * 16 + g * 4 + r;
            if (grow < N) {
                short4v o;
                o[0] = (short)bf16_rne(acc2[0][r]);
                o[1] = (short)bf16_rne(acc2[1][r]);
                o[2] = (short)bf16_rne(acc2[2][r]);
                o[3] = (short)bf16_rne(acc2[3][r]);
                *reinterpret_cast<short4v*>(v + (long long)grow * 64 + c4) = o;
            }
        }
    }
}

// ---------------- decoder: per-wave, shfl-reduce tail (OUT=3) ----------------
__global__ __launch_bounds__(256, 4) void k_dec_mf(
    const float* __restrict__ n, const short* __restrict__ wfW1, const float* __restrict__ b1,
    const float* __restrict__ W2, const float* __restrict__ b2,
    float* __restrict__ out, int N)
{
    __shared__ short An[8192];
    const int row0 = blockIdx.x * 64;
    const int lane = threadIdx.x & 63;
    const int wm = threadIdx.x >> 6;
    const int g = lane >> 4, c = lane & 15;
    const int c4 = c << 2;
    const int rowA = wm * 16 + c;
    stageW(n, row0, N, An, wm, lane);
    __builtin_amdgcn_wave_barrier();
    const f32x4 z4 = {0.f, 0.f, 0.f, 0.f};
    f32x4 acc[4];
    #pragma unroll
    for (int t = 0; t < 4; ++t) acc[t] = z4;
    gemm64(An, wfW1, rowA, g, lane, acc);
    const float4 b1q = *reinterpret_cast<const float4*>(b1 + c4);
    const float b1a[4] = {b1q.x, b1q.y, b1q.z, b1q.w};
    #pragma unroll
    for (int t = 0; t < 4; ++t)
        #pragma unroll
        for (int r = 0; r < 4; ++r) acc[t][r] = lrelu(acc[t][r] + b1a[t]);
    const float4 w0 = *reinterpret_cast<const float4*>(W2 + c4 * 3);
    const float4 w1 = *reinterpret_cast<const float4*>(W2 + c4 * 3 + 4);
    const float4 w2 = *reinterpret_cast<const float4*>(W2 + c4 * 3 + 8);
    const float wv[12] = {w0.x,w0.y,w0.z,w0.w, w1.x,w1.y,w1.z,w1.w, w2.x,w2.y,w2.z,w2.w};
    float po[4][3];
    #pragma unroll
    for (int r = 0; r < 4; ++r)
        #pragma unroll
        for (int o = 0; o < 3; ++o)
            po[r][o] = acc[0][r]*wv[o] + acc[1][r]*wv[3+o] + acc[2][r]*wv[6+o] + acc[3][r]*wv[9+o];
    #pragma unroll
    for (int m = 1; m <= 8; m <<= 1)
        #pragma unroll
        for (int r = 0; r < 4; ++r)
            #pragma unroll
            for (int o = 0; o < 3; ++o)
                po[r][o] += __shfl_xor(po[r][o], m);
    if (c < 3) {
        #pragma unroll
        for (int r = 0; r < 4; ++r) {
            const int grow = row0 + wm * 16 + g * 4 + r;
            const float val = (c == 0) ? po[r][0] : (c == 1) ? po[r][1] : po[r][2];
            if (grow < N) out[(long long)grow * 3 + c] = b2[c] + val;
        }
    }
}

// ================= CSR build =================
__global__ void k_hist(const int* __restrict__ eidx, int* __restrict__ cnt, int E)
{
    int i = blockIdx.x * 256 + threadIdx.x;
    if (i < E) atomicAdd(&cnt[eidx[2 * i]], 1);
}

__global__ void k_scan1(const int* __restrict__ cnt, int* __restrict__ starts,
                        int* __restrict__ bsum, int n)
{
    __shared__ int sh[256];
    const int tid = threadIdx.x;
    const int i = blockIdx.x * 256 + tid;
    const int val = (i < n) ? cnt[i] : 0;
    sh[tid] = val; __syncthreads();
    for (int off = 1; off < 256; off <<= 1) {
        int t = (tid >= off) ? sh[tid - off] : 0;
        __syncthreads();
        sh[tid] += t;
        __syncthreads();
    }
    if (i < n) starts[i] = sh[tid] - val;
    if (tid == 255) bsum[blockIdx.x] = sh[255];
}

__global__ void k_scan2(int* __restrict__ bsum, int nb)
{
    __shared__ int sh[256];
    const int tid = threadIdx.x;
    const int val = (tid < nb) ? bsum[tid] : 0;
    sh[tid] = val; __syncthreads();
    for (int off = 1; off < 256; off <<= 1) {
        int t = (tid >= off) ? sh[tid - off] : 0;
        __syncthreads();
        sh[tid] += t;
        __syncthreads();
    }
    if (tid < nb) bsum[tid] = sh[tid] - val;
}

__global__ void k_scan3(int* __restrict__ starts, const int* __restrict__ bsum, int n)
{
    int i = blockIdx.x * 256 + threadIdx.x;
    if (i < n) starts[i] += bsum[blockIdx.x];
}

__global__ void k_scatter(const int* __restrict__ eidx, const int* __restrict__ starts,
                          int* __restrict__ cursor, int* __restrict__ csr,
                          int* __restrict__ sp, int* __restrict__ rp, int E)
{
    int i = blockIdx.x * 256 + threadIdx.x;
    if (i < E) {
        const int s = eidx[2 * i];
        const int p = atomicAdd(&cursor[s], 1);
        const int q = starts[s] + p;
        csr[q] = i;
        sp[q] = s;
        rp[q] = eidx[2 * i + 1];
    }
}

extern "C" void kernel_launch(void* const* d_in, const int* in_sizes, int n_in,
                              void* d_out, int out_size, void* d_ws, size_t ws_size,
                              hipStream_t stream)
{
    (void)in_sizes; (void)n_in; (void)out_size; (void)ws_size;
    constexpr int N = 50000, E = 300000, L = 3;

    const float* nodes = (const float*)d_in[0];
    const float* edges = (const float*)d_in[1];
    const int*   eidx  = (const int*)d_in[2];
    const float* neW1 = (const float*)d_in[3];
    const float* neb1 = (const float*)d_in[4];
    const float* neW2 = (const float*)d_in[5];
    const float* neb2 = (const float*)d_in[6];
    const float* neg  = (const float*)d_in[7];
    const float* nebe = (const float*)d_in[8];
    const float* eeW1 = (const float*)d_in[9];
    const float* eeb1 = (const float*)d_in[10];
    const float* eeW2 = (const float*)d_in[11];
    const float* eeb2 = (const float*)d_in[12];
    const float* eeg  = (const float*)d_in[13];
    const float* eebe = (const float*)d_in[14];
    const float* nmW1 = (const float*)d_in[15];
    const float* nmb1 = (const float*)d_in[16];
    const float* nmW2 = (const float*)d_in[17];
    const float* nmb2 = (const float*)d_in[18];
    const float* nmg  = (const float*)d_in[19];
    const float* nmbe = (const float*)d_in[20];
    const float* emW1 = (const float*)d_in[21];
    const float* emb1 = (const float*)d_in[22];
    const float* emW2 = (const float*)d_in[23];
    const float* emb2 = (const float*)d_in[24];
    const float* emg  = (const float*)d_in[25];
    const float* embe = (const float*)d_in[26];
    const float* decW1 = (const float*)d_in[27];
    const float* decb1 = (const float*)d_in[28];
    const float* decW2 = (const float*)d_in[29];
    const float* decb2 = (const float*)d_in[30];

    // workspace: n(f32) | aggr(f32) | ubf | vbf | ints | wf | ebf
    float* n    = (float*)d_ws;                       // N*64 f32
    float* aggr = n + (size_t)N * 64;                 // N*64 f32
    unsigned short* ubf = (unsigned short*)(aggr + (size_t)N * 64);  // N*64 bf16
    unsigned short* vbf = ubf + (size_t)N * 64;       // N*64 bf16
    int* cnt    = (int*)(vbf + (size_t)N * 64);       // N
    int* starts = cnt + N;                            // N
    int* csr    = starts + N;                         // E
    int* bsum   = csr + E;                            // 256
    int* cursor = bsum + 256;                         // N
    int* sp     = cursor + N;                         // E
    int* rp     = sp + E;                             // E
    short* wf   = (short*)(rp + E);                   // 24 * 8192 shorts
    unsigned short* ebf = (unsigned short*)(wf + (size_t)24 * 8192);  // E*64 bf16

    const int nbN = (N + 255) / 256;
    const int nbE = (E + 255) / 256;
    const int nbN64 = (N + 63) / 64;            // 782
    const int nbE64 = (E + 63) / 64;            // 4688

    const short* wfEE  = wf + (size_t)21 * 8192;
    const short* wfNE  = wf + (size_t)22 * 8192;
    const short* wfDec = wf + (size_t)23 * 8192;

    // ---- weight fragment prep + CSR build ----
    k_prepw<<<24, 256, 0, stream>>>(emW1, emW2, nmW1, nmW2, eeW2, neW2, decW1, wf);
    hipMemsetAsync(cnt, 0, (size_t)N * sizeof(int), stream);
    hipMemsetAsync(cursor, 0, (size_t)N * sizeof(int), stream);
    k_hist<<<nbE, 256, 0, stream>>>(eidx, cnt, E);
    k_scan1<<<nbN, 256, 0, stream>>>(cnt, starts, bsum, N);
    k_scan2<<<1, 256, 0, stream>>>(bsum, nbN);
    k_scan3<<<nbN, 256, 0, stream>>>(starts, bsum, N);
    k_scatter<<<nbE, 256, 0, stream>>>(eidx, starts, cursor, csr, sp, rp, E);

    // ---- encode (node encoder also emits u,v for layer 0; edge encoder writes bf16 e) ----
    const short* wl0 = wf;
    k_enc_mf<16, false, true, false><<<nbN64, 256, 0, stream>>>(
        nodes, nullptr, neW1, neb1, wfNE, neb2, neg, nebe, n,
        wl0 + 8192, wl0 + 2 * 8192, ubf, vbf, N);
    k_enc_mf<8, true, false, true><<<nbE64, 256, 0, stream>>>(
        edges, csr, eeW1, eeb1, wfEE, eeb2, eeg, eebe, (float*)ebf,
        nullptr, nullptr, nullptr, nullptr, E);

    // ---- message-passing layers ----
    for (int i = 0; i < L; ++i) {
        const short* wl = wf + (size_t)i * 7 * 8192;
        k_edge_mf<<<nbE64, 256, 0, stream>>>(ebf, sp, rp, ubf, vbf, wl, wl + 3 * 8192,
                                             emb1 + i * 64, emb2 + i * 64,
                                             emg + i * 64, embe + i * 64, E);
        k_aggr<<<(N + 3) / 4, 256, 0, stream>>>(ebf, starts, cnt, aggr, N);
        const short* wln = (i + 1 < L) ? wf + (size_t)(i + 1) * 7 * 8192 : nullptr;
        k_node_mf<<<nbN64, 256, 0, stream>>>(n, aggr,
                                             wl + 4 * 8192, wl + 5 * 8192, wl + 6 * 8192,
                                             nmb1 + i * 64, nmb2 + i * 64,
                                             nmg + i * 64, nmbe + i * 64,
                                             wln ? wln + 8192 : nullptr,
                                             wln ? wln + 2 * 8192 : nullptr,
                                             ubf, vbf, N);
    }
    k_dec_mf<<<nbN64, 256, 0, stream>>>(n, wfDec, decb1, decW2, decb2, (float*)d_out, N);
}

// Round 16
// 396.923 us; speedup vs baseline: 1.1709x; 1.0087x over previous
//
#include <hip/hip_runtime.h>

typedef __attribute__((ext_vector_type(8))) short short8v;
typedef __attribute__((ext_vector_type(4))) short short4v;
typedef __attribute__((ext_vector_type(4))) float f32x4;

__device__ __forceinline__ float lrelu(float x) { return x >= 0.f ? x : 0.05f * x; }

__device__ __forceinline__ unsigned short bf16_rne(float x) {
    unsigned u = __float_as_uint(x);
    u += 0x7FFFu + ((u >> 16) & 1u);
    return (unsigned short)(u >> 16);
}
__device__ __forceinline__ float bf16_to_f(unsigned short h) {
    return __uint_as_float(((unsigned)h) << 16);
}
__device__ __forceinline__ void split2(float x, unsigned short& hi, unsigned short& lo) {
    hi = bf16_rne(x);
    lo = bf16_rne(x - bf16_to_f(hi));
}

// ================= MFMA machinery =================
// A-frag (M=16,K=32): lane holds A[row=lane&15][k=(lane>>4)*8+i]
// B-frag: lane holds B[k][frag col16=lane&15]; COLUMN INTERLEAVE: frag t, col16 c -> global col 4c+t.
// C/D: col16=lane&15, row=(lane>>4)*4+reg
// LDS A layout per plane: A[row][k] shorts, 16B slots XOR-swizzled: slot=(k>>3)^(row&7); lo plane at +4096.
// Precision: weights hi/lo; staged fp32 tensors (n, aggr) hi/lo; e/u/v global bf16;
// hidden activations H single bf16.
// Locked lessons: no in-thread multi-tile pipelining (r9/10: spills); no min-waves
// launch_bounds above 4 (r13/14: VGPR clamp -> spills). Round-16: decoder fused into
// layer-3 k_node (n never hits HBM at the end); XCD swizzle on k_edge block ids.

__device__ __forceinline__ void stageW(const float* src, int row0, int nrows,
                                       short* __restrict__ A, int wm, int lane)
{
    #pragma unroll
    for (int it = 0; it < 4; ++it) {
        const int q = it * 64 + lane;
        const int rl = wm * 16 + (q >> 4);
        const int k0 = (q & 15) << 2;
        const int grow = row0 + rl;
        float4 x = (grow < nrows) ? *reinterpret_cast<const float4*>(src + (long long)grow * 64 + k0)
                                  : make_float4(0.f, 0.f, 0.f, 0.f);
        unsigned short h0,h1,h2,h3,l0,l1,l2,l3;
        split2(x.x, h0, l0); split2(x.y, h1, l1); split2(x.z, h2, l2); split2(x.w, h3, l3);
        const int off = rl * 64 + ((((k0 >> 3) ^ (rl & 7))) << 3) + (k0 & 7);
        short4v hv; hv[0]=(short)h0; hv[1]=(short)h1; hv[2]=(short)h2; hv[3]=(short)h3;
        short4v lv; lv[0]=(short)l0; lv[1]=(short)l1; lv[2]=(short)l2; lv[3]=(short)l3;
        *reinterpret_cast<short4v*>(A + off) = hv;
        *reinterpret_cast<short4v*>(A + 4096 + off) = lv;
    }
}

__device__ __forceinline__ void gemm64(const short* __restrict__ A, const short* __restrict__ wf,
                                       int row, int g, int lane, f32x4* __restrict__ acc)
{
    #pragma unroll
    for (int s = 0; s < 2; ++s) {
        const int k8 = s * 4 + g;
        const int aoff = row * 64 + ((k8 ^ (row & 7)) << 3);
        const short8v a_hi = *reinterpret_cast<const short8v*>(A + aoff);
        const short8v a_lo = *reinterpret_cast<const short8v*>(A + 4096 + aoff);
        #pragma unroll
        for (int t = 0; t < 4; ++t) {
            const short8v b_hi = *reinterpret_cast<const short8v*>(wf + ((s*4+t)*2+0)*512 + lane*8);
            const short8v b_lo = *reinterpret_cast<const short8v*>(wf + ((s*4+t)*2+1)*512 + lane*8);
            acc[t] = __builtin_amdgcn_mfma_f32_16x16x32_bf16(a_hi, b_hi, acc[t], 0, 0, 0);
            acc[t] = __builtin_amdgcn_mfma_f32_16x16x32_bf16(a_lo, b_hi, acc[t], 0, 0, 0);
            acc[t] = __builtin_amdgcn_mfma_f32_16x16x32_bf16(a_hi, b_lo, acc[t], 0, 0, 0);
        }
    }
}

__device__ __forceinline__ void gemm64h(const short* __restrict__ A, const short* __restrict__ wf,
                                        int row, int g, int lane, f32x4* __restrict__ acc)
{
    #pragma unroll
    for (int s = 0; s < 2; ++s) {
        const int k8 = s * 4 + g;
        const int aoff = row * 64 + ((k8 ^ (row & 7)) << 3);
        const short8v a = *reinterpret_cast<const short8v*>(A + aoff);
        #pragma unroll
        for (int t = 0; t < 4; ++t) {
            const short8v b_hi = *reinterpret_cast<const short8v*>(wf + ((s*4+t)*2+0)*512 + lane*8);
            const short8v b_lo = *reinterpret_cast<const short8v*>(wf + ((s*4+t)*2+1)*512 + lane*8);
            acc[t] = __builtin_amdgcn_mfma_f32_16x16x32_bf16(a, b_hi, acc[t], 0, 0, 0);
            acc[t] = __builtin_amdgcn_mfma_f32_16x16x32_bf16(a, b_lo, acc[t], 0, 0, 0);
        }
    }
}

__device__ __forceinline__ void repack1(short* __restrict__ A, const float4* __restrict__ q,
                                        int wm, int g, int c4)
{
    #pragma unroll
    for (int r = 0; r < 4; ++r) {
        const int rl = wm * 16 + g * 4 + r;
        const int off = rl * 64 + (((c4 >> 3) ^ (rl & 7)) << 3) + (c4 & 7);
        short4v hv;
        hv[0] = (short)bf16_rne(q[r].x);
        hv[1] = (short)bf16_rne(q[r].y);
        hv[2] = (short)bf16_rne(q[r].z);
        hv[3] = (short)bf16_rne(q[r].w);
        *reinterpret_cast<short4v*>(A + off) = hv;
    }
}

// hi/lo repack (exact) into both planes
__device__ __forceinline__ void repackW(short* __restrict__ A, const float4* __restrict__ q,
                                        int wm, int g, int c4)
{
    #pragma unroll
    for (int r = 0; r < 4; ++r) {
        const int rl = wm * 16 + g * 4 + r;
        const int off = rl * 64 + (((c4 >> 3) ^ (rl & 7)) << 3) + (c4 & 7);
        unsigned short h0,h1,h2,h3,l0,l1,l2,l3;
        split2(q[r].x, h0, l0); split2(q[r].y, h1, l1); split2(q[r].z, h2, l2); split2(q[r].w, h3, l3);
        short4v hv; hv[0]=(short)h0; hv[1]=(short)h1; hv[2]=(short)h2; hv[3]=(short)h3;
        short4v lv; lv[0]=(short)l0; lv[1]=(short)l1; lv[2]=(short)l2; lv[3]=(short)l3;
        *reinterpret_cast<short4v*>(A + off) = hv;
        *reinterpret_cast<short4v*>(A + 4096 + off) = lv;
    }
}

// Preformat 64x64 fp32 W[k][col] chunks -> hi/lo B-fragments (interleaved col map).
__global__ void k_prepw(const float* __restrict__ emW1, const float* __restrict__ emW2,
                        const float* __restrict__ nmW1, const float* __restrict__ nmW2,
                        const float* __restrict__ eeW2, const float* __restrict__ neW2,
                        const float* __restrict__ decW1,
                        short* __restrict__ wf)
{
    const int cid = blockIdx.x;
    const float* src;
    if (cid < 21) {
        const int layer = cid / 7, j = cid % 7;
        src =
            j == 0 ? emW1 + (size_t)layer * 12288 :
            j == 1 ? emW1 + (size_t)layer * 12288 + 4096 :
            j == 2 ? emW1 + (size_t)layer * 12288 + 8192 :
            j == 3 ? emW2 + (size_t)layer * 4096 :
            j == 4 ? nmW1 + (size_t)layer * 8192 :
            j == 5 ? nmW1 + (size_t)layer * 8192 + 4096 :
                     nmW2 + (size_t)layer * 4096;
    } else {
        src = (cid == 21) ? eeW2 : (cid == 22) ? neW2 : decW1;
    }
    short* dst = wf + (size_t)cid * 8192;
    for (int fr = threadIdx.x; fr < 1024; fr += 256) {
        const int lane = fr & 63;
        const int stp = fr >> 6;
        const int p = stp & 1;
        const int st = stp >> 1;
        const int s = st >> 2, t = st & 3;
        const int col = ((lane & 15) << 2) + t;
        const int k0 = s * 32 + (lane >> 4) * 8;
        short8v o;
        #pragma unroll
        for (int i = 0; i < 8; ++i) {
            const float w = src[(k0 + i) * 64 + col];
            const unsigned short hi = bf16_rne(w);
            o[i] = (short)(p ? bf16_rne(w - bf16_to_f(hi)) : hi);
        }
        *reinterpret_cast<short8v*>(dst + fr * 8) = o;
    }
}

// ---------------- encoder; MAKEUV: also emit u,v (bf16); OUTBF16: bf16 output (edge stream) ----------------
template<int DIN, bool PERM, bool MAKEUV, bool OUTBF16>
__global__ __launch_bounds__(256, 4) void k_enc_mf(
    const float* __restrict__ x, const int* __restrict__ csr,
    const float* __restrict__ W1, const float* __restrict__ b1,
    const short* __restrict__ wfW2, const float* __restrict__ b2,
    const float* __restrict__ gam, const float* __restrict__ bet,
    float* __restrict__ out,
    const short* __restrict__ wfB, const short* __restrict__ wfC,
    unsigned short* __restrict__ u, unsigned short* __restrict__ v, int nrows)
{
    __shared__ short Hf[4096];
    const int row0 = blockIdx.x * 64;
    const int lane = threadIdx.x & 63;
    const int wm = threadIdx.x >> 6;
    const int g = lane >> 4, c = lane & 15;
    const int c4 = c << 2;
    const int rowA = wm * 16 + c;

    long long orig[4];
    #pragma unroll
    for (int r = 0; r < 4; ++r) {
        const int grow = row0 + wm * 16 + g * 4 + r;
        orig[r] = (grow < nrows) ? (long long)(PERM ? csr[grow] : grow) : -1;
    }

    const f32x4 z4 = {0.f, 0.f, 0.f, 0.f};
    f32x4 acc[4];
    #pragma unroll
    for (int t = 0; t < 4; ++t) acc[t] = z4;

    #pragma unroll
    for (int kq = 0; kq < DIN / 4; ++kq) {
        float xv[4][4];
        #pragma unroll
        for (int r = 0; r < 4; ++r) {
            float4 t4 = make_float4(0.f, 0.f, 0.f, 0.f);
            if (orig[r] >= 0)
                t4 = *reinterpret_cast<const float4*>(x + orig[r] * DIN + kq * 4);
            xv[r][0] = t4.x; xv[r][1] = t4.y; xv[r][2] = t4.z; xv[r][3] = t4.w;
        }
        #pragma unroll
        for (int i = 0; i < 4; ++i) {
            const int k = kq * 4 + i;
            const float4 w4 = *reinterpret_cast<const float4*>(W1 + k * 64 + c4);
            const float wv[4] = {w4.x, w4.y, w4.z, w4.w};
            #pragma unroll
            for (int t = 0; t < 4; ++t)
                #pragma unroll
                for (int r = 0; r < 4; ++r)
                    acc[t][r] = fmaf(xv[r][i], wv[t], acc[t][r]);
        }
    }

    const float4 b1q = *reinterpret_cast<const float4*>(b1 + c4);
    float4 hq[4];
    #pragma unroll
    for (int r = 0; r < 4; ++r) {
        hq[r].x = lrelu(acc[0][r] + b1q.x);
        hq[r].y = lrelu(acc[1][r] + b1q.y);
        hq[r].z = lrelu(acc[2][r] + b1q.z);
        hq[r].w = lrelu(acc[3][r] + b1q.w);
    }
    repack1(Hf, hq, wm, g, c4);
    __builtin_amdgcn_wave_barrier();

    f32x4 acc2[4];
    #pragma unroll
    for (int t = 0; t < 4; ++t) acc2[t] = z4;
    gemm64h(Hf, wfW2, rowA, g, lane, acc2);

    const float4 b2q = *reinterpret_cast<const float4*>(b2 + c4);
    const float b2a[4] = {b2q.x, b2q.y, b2q.z, b2q.w};
    #pragma unroll
    for (int t = 0; t < 4; ++t) {
        #pragma unroll
        for (int r = 0; r < 4; ++r) acc2[t][r] = lrelu(acc2[t][r] + b2a[t]);
    }
    const float4 gq = *reinterpret_cast<const float4*>(gam + c4);
    const float4 bq = *reinterpret_cast<const float4*>(bet + c4);
    float4 nq[4];
    #pragma unroll
    for (int r = 0; r < 4; ++r) {
        float s = acc2[0][r] + acc2[1][r] + acc2[2][r] + acc2[3][r];
        s += __shfl_xor(s, 1); s += __shfl_xor(s, 2); s += __shfl_xor(s, 4); s += __shfl_xor(s, 8);
        const float mu = s * 0.015625f;
        float q = 0.f;
        #pragma unroll
        for (int t = 0; t < 4; ++t) { const float d = acc2[t][r] - mu; q = fmaf(d, d, q); }
        q += __shfl_xor(q, 1); q += __shfl_xor(q, 2); q += __shfl_xor(q, 4); q += __shfl_xor(q, 8);
        const float rs = rsqrtf(q * 0.015625f + 1e-5f);
        nq[r].x = (acc2[0][r] - mu) * rs * gq.x + bq.x;
        nq[r].y = (acc2[1][r] - mu) * rs * gq.y + bq.y;
        nq[r].z = (acc2[2][r] - mu) * rs * gq.z + bq.z;
        nq[r].w = (acc2[3][r] - mu) * rs * gq.w + bq.w;
        const int grow = row0 + wm * 16 + g * 4 + r;
        if (grow < nrows) {
            if constexpr (OUTBF16) {
                short4v st;
                st[0] = (short)bf16_rne(nq[r].x);
                st[1] = (short)bf16_rne(nq[r].y);
                st[2] = (short)bf16_rne(nq[r].z);
                st[3] = (short)bf16_rne(nq[r].w);
                *reinterpret_cast<short4v*>(reinterpret_cast<unsigned short*>(out) + (long long)grow * 64 + c4) = st;
            } else {
                *reinterpret_cast<float4*>(out + (long long)grow * 64 + c4) = nq[r];
            }
        }
    }

    if constexpr (MAKEUV) {
        __builtin_amdgcn_wave_barrier();
        repack1(Hf, nq, wm, g, c4);
        __builtin_amdgcn_wave_barrier();
        #pragma unroll
        for (int t = 0; t < 4; ++t) acc2[t] = z4;
        gemm64h(Hf, wfB, rowA, g, lane, acc2);
        #pragma unroll
        for (int r = 0; r < 4; ++r) {
            const int grow = row0 + wm * 16 + g * 4 + r;
            if (grow < nrows) {
                short4v o;
                o[0] = (short)bf16_rne(acc2[0][r]);
                o[1] = (short)bf16_rne(acc2[1][r]);
                o[2] = (short)bf16_rne(acc2[2][r]);
                o[3] = (short)bf16_rne(acc2[3][r]);
                *reinterpret_cast<short4v*>(u + (long long)grow * 64 + c4) = o;
            }
        }
        #pragma unroll
        for (int t = 0; t < 4; ++t) acc2[t] = z4;
        gemm64h(Hf, wfC, rowA, g, lane, acc2);
        #pragma unroll
        for (int r = 0; r < 4; ++r) {
            const int grow = row0 + wm * 16 + g * 4 + r;
            if (grow < nrows) {
                short4v o;
                o[0] = (short)bf16_rne(acc2[0][r]);
                o[1] = (short)bf16_rne(acc2[1][r]);
                o[2] = (short)bf16_rne(acc2[2][r]);
                o[3] = (short)bf16_rne(acc2[3][r]);
                *reinterpret_cast<short4v*>(v + (long long)grow * 64 + c4) = o;
            }
        }
    }
}

// ---------------- edge update: e(bf16) += LN(lrelu(lrelu(e@A + u[s] + v[r] + b1)@W2 + b2)) ----
// XCD-aware bijective block swizzle (gridDim.x % 8 == 0): contiguous CSR ranges per XCD.
__global__ __launch_bounds__(256, 4) void k_edge_mf(
    unsigned short* ebf, const int* __restrict__ sp, const int* __restrict__ rp,
    const unsigned short* __restrict__ u, const unsigned short* __restrict__ v,
    const short* __restrict__ wfA, const short* __restrict__ wfW2,
    const float* __restrict__ b1, const float* __restrict__ b2,
    const float* __restrict__ gam, const float* __restrict__ bet, int E)
{
    __shared__ short Hf[4096];
    const int nwg = gridDim.x;
    const int bid = blockIdx.x;
    const int swz = ((nwg & 7) == 0) ? (bid & 7) * (nwg >> 3) + (bid >> 3) : bid;
    const int row0 = swz * 64;
    const int lane = threadIdx.x & 63;
    const int wm = threadIdx.x >> 6;
    const int g = lane >> 4, c = lane & 15;
    const int c4 = c << 2;
    const int rowA = wm * 16 + c;

    int sidx[4], ridx[4];
    #pragma unroll
    for (int r = 0; r < 4; ++r) {
        const int grow = row0 + wm * 16 + g * 4 + r;
        if (grow < E) { sidx[r] = sp[grow]; ridx[r] = rp[grow]; }
        else          { sidx[r] = 0; ridx[r] = 0; }
    }
    const int arow = (row0 + rowA < E) ? row0 + rowA : 0;
    const short8v a0 = *reinterpret_cast<const short8v*>(ebf + (long long)arow * 64 + g * 8);
    const short8v a1 = *reinterpret_cast<const short8v*>(ebf + (long long)arow * 64 + 32 + g * 8);
    short4v eold[4];
    #pragma unroll
    for (int r = 0; r < 4; ++r) {
        const int grow = row0 + wm * 16 + g * 4 + r;
        const int rc = (grow < E) ? grow : 0;
        eold[r] = *reinterpret_cast<const short4v*>(ebf + (long long)rc * 64 + c4);
    }
    short4v us[4], vs[4];
    #pragma unroll
    for (int r = 0; r < 4; ++r) {
        us[r] = *reinterpret_cast<const short4v*>(u + (long long)sidx[r] * 64 + c4);
        vs[r] = *reinterpret_cast<const short4v*>(v + (long long)ridx[r] * 64 + c4);
    }

    const f32x4 z4 = {0.f, 0.f, 0.f, 0.f};
    f32x4 acc[4];
    #pragma unroll
    for (int t = 0; t < 4; ++t) acc[t] = z4;
    #pragma unroll
    for (int s = 0; s < 2; ++s) {
        const short8v a = s ? a1 : a0;
        #pragma unroll
        for (int t = 0; t < 4; ++t) {
            const short8v b_hi = *reinterpret_cast<const short8v*>(wfA + ((s*4+t)*2+0)*512 + lane*8);
            const short8v b_lo = *reinterpret_cast<const short8v*>(wfA + ((s*4+t)*2+1)*512 + lane*8);
            acc[t] = __builtin_amdgcn_mfma_f32_16x16x32_bf16(a, b_hi, acc[t], 0, 0, 0);
            acc[t] = __builtin_amdgcn_mfma_f32_16x16x32_bf16(a, b_lo, acc[t], 0, 0, 0);
        }
    }

    const float4 b1q = *reinterpret_cast<const float4*>(b1 + c4);
    float4 hq[4];
    #pragma unroll
    for (int r = 0; r < 4; ++r) {
        hq[r].x = lrelu(acc[0][r] + b1q.x + bf16_to_f((unsigned short)us[r][0]) + bf16_to_f((unsigned short)vs[r][0]));
        hq[r].y = lrelu(acc[1][r] + b1q.y + bf16_to_f((unsigned short)us[r][1]) + bf16_to_f((unsigned short)vs[r][1]));
        hq[r].z = lrelu(acc[2][r] + b1q.z + bf16_to_f((unsigned short)us[r][2]) + bf16_to_f((unsigned short)vs[r][2]));
        hq[r].w = lrelu(acc[3][r] + b1q.w + bf16_to_f((unsigned short)us[r][3]) + bf16_to_f((unsigned short)vs[r][3]));
    }
    repack1(Hf, hq, wm, g, c4);
    __builtin_amdgcn_wave_barrier();

    f32x4 acc2[4];
    #pragma unroll
    for (int t = 0; t < 4; ++t) acc2[t] = z4;
    gemm64h(Hf, wfW2, rowA, g, lane, acc2);

    const float4 b2q = *reinterpret_cast<const float4*>(b2 + c4);
    const float b2a[4] = {b2q.x, b2q.y, b2q.z, b2q.w};
    #pragma unroll
    for (int t = 0; t < 4; ++t) {
        #pragma unroll
        for (int r = 0; r < 4; ++r) acc2[t][r] = lrelu(acc2[t][r] + b2a[t]);
    }
    const float4 gq = *reinterpret_cast<const float4*>(gam + c4);
    const float4 bq = *reinterpret_cast<const float4*>(bet + c4);
    #pragma unroll
    for (int r = 0; r < 4; ++r) {
        float s = acc2[0][r] + acc2[1][r] + acc2[2][r] + acc2[3][r];
        s += __shfl_xor(s, 1); s += __shfl_xor(s, 2); s += __shfl_xor(s, 4); s += __shfl_xor(s, 8);
        const float mu = s * 0.015625f;
        float q = 0.f;
        #pragma unroll
        for (int t = 0; t < 4; ++t) { const float d = acc2[t][r] - mu; q = fmaf(d, d, q); }
        q += __shfl_xor(q, 1); q += __shfl_xor(q, 2); q += __shfl_xor(q, 4); q += __shfl_xor(q, 8);
        const float rs = rsqrtf(q * 0.015625f + 1e-5f);
        const int grow = row0 + wm * 16 + g * 4 + r;
        if (grow < E) {
            float ox = (acc2[0][r] - mu) * rs * gq.x + bq.x + bf16_to_f((unsigned short)eold[r][0]);
            float oy = (acc2[1][r] - mu) * rs * gq.y + bq.y + bf16_to_f((unsigned short)eold[r][1]);
            float oz = (acc2[2][r] - mu) * rs * gq.z + bq.z + bf16_to_f((unsigned short)eold[r][2]);
            float ow = (acc2[3][r] - mu) * rs * gq.w + bq.w + bf16_to_f((unsigned short)eold[r][3]);
            short4v st;
            st[0] = (short)bf16_rne(ox);
            st[1] = (short)bf16_rne(oy);
            st[2] = (short)bf16_rne(oz);
            st[3] = (short)bf16_rne(ow);
            *reinterpret_cast<short4v*>(ebf + (long long)grow * 64 + c4) = st;
        }
    }
}

// ---------------- aggregation: wave per node, lane = column, coalesced bf16 CSR scan ----------------
__global__ __launch_bounds__(256) void k_aggr(
    const unsigned short* __restrict__ ebf, const int* __restrict__ starts,
    const int* __restrict__ cnt, float* __restrict__ aggr, int N)
{
    const int node = blockIdx.x * 4 + (threadIdx.x >> 6);
    if (node >= N) return;
    const int j = threadIdx.x & 63;
    const int st = starts[node], en = st + cnt[node];
    float a = 0.f;
    for (int t = st; t < en; ++t)
        a += bf16_to_f(ebf[(long long)t * 64 + j]);
    aggr[(long long)node * 64 + j] = a;
}

// ---------------- node update: n += MLP(concat[n, aggr]); fused uv OR fused decoder ----------------
__global__ __launch_bounds__(256, 4) void k_node_mf(
    float* n, const float* aggr,
    const short* __restrict__ wfW1a, const short* __restrict__ wfW1b, const short* __restrict__ wfW2,
    const float* __restrict__ b1, const float* __restrict__ b2,
    const float* __restrict__ gam, const float* __restrict__ bet,
    const short* __restrict__ wfB, const short* __restrict__ wfC,
    unsigned short* __restrict__ u, unsigned short* __restrict__ v,
    const short* __restrict__ wfDec, const float* __restrict__ db1,
    const float* __restrict__ dW2, const float* __restrict__ db2,
    float* __restrict__ out, int N)
{
    __shared__ short An[8192];
    __shared__ short Aa[8192];
    const int row0 = blockIdx.x * 64;
    const int lane = threadIdx.x & 63;
    const int wm = threadIdx.x >> 6;
    const int g = lane >> 4, c = lane & 15;
    const int c4 = c << 2;
    const int rowA = wm * 16 + c;

    stageW(n, row0, N, An, wm, lane);
    stageW(aggr, row0, N, Aa, wm, lane);
    __builtin_amdgcn_wave_barrier();

    const f32x4 z4 = {0.f, 0.f, 0.f, 0.f};
    f32x4 acc[4];
    #pragma unroll
    for (int t = 0; t < 4; ++t) acc[t] = z4;
    gemm64(An, wfW1a, rowA, g, lane, acc);
    gemm64(Aa, wfW1b, rowA, g, lane, acc);

    const float4 b1q = *reinterpret_cast<const float4*>(b1 + c4);
    float4 hq[4];
    #pragma unroll
    for (int r = 0; r < 4; ++r) {
        hq[r].x = lrelu(acc[0][r] + b1q.x);
        hq[r].y = lrelu(acc[1][r] + b1q.y);
        hq[r].z = lrelu(acc[2][r] + b1q.z);
        hq[r].w = lrelu(acc[3][r] + b1q.w);
    }
    __builtin_amdgcn_wave_barrier();
    repack1(Aa, hq, wm, g, c4);        // Aa dead after gemm -> overlay (hi plane only)
    __builtin_amdgcn_wave_barrier();

    f32x4 acc2[4];
    #pragma unroll
    for (int t = 0; t < 4; ++t) acc2[t] = z4;
    gemm64h(Aa, wfW2, rowA, g, lane, acc2);

    const float4 b2q = *reinterpret_cast<const float4*>(b2 + c4);
    const float b2a[4] = {b2q.x, b2q.y, b2q.z, b2q.w};
    #pragma unroll
    for (int t = 0; t < 4; ++t) {
        #pragma unroll
        for (int r = 0; r < 4; ++r) acc2[t][r] = lrelu(acc2[t][r] + b2a[t]);
    }
    const float4 gq = *reinterpret_cast<const float4*>(gam + c4);
    const float4 bq = *reinterpret_cast<const float4*>(bet + c4);
    float4 nq[4];
    #pragma unroll
    for (int r = 0; r < 4; ++r) {
        float s = acc2[0][r] + acc2[1][r] + acc2[2][r] + acc2[3][r];
        s += __shfl_xor(s, 1); s += __shfl_xor(s, 2); s += __shfl_xor(s, 4); s += __shfl_xor(s, 8);
        const float mu = s * 0.015625f;
        float q = 0.f;
        #pragma unroll
        for (int t = 0; t < 4; ++t) { const float d = acc2[t][r] - mu; q = fmaf(d, d, q); }
        q += __shfl_xor(q, 1); q += __shfl_xor(q, 2); q += __shfl_xor(q, 4); q += __shfl_xor(q, 8);
        const float rs = rsqrtf(q * 0.015625f + 1e-5f);
        const int rl = wm * 16 + g * 4 + r;
        const int off = rl * 64 + (((c4 >> 3) ^ (rl & 7)) << 3) + (c4 & 7);
        const short4v nh = *reinterpret_cast<const short4v*>(An + off);
        const short4v nl = *reinterpret_cast<const short4v*>(An + 4096 + off);
        nq[r].x = (acc2[0][r] - mu) * rs * gq.x + bq.x + bf16_to_f((unsigned short)nh[0]) + bf16_to_f((unsigned short)nl[0]);
        nq[r].y = (acc2[1][r] - mu) * rs * gq.y + bq.y + bf16_to_f((unsigned short)nh[1]) + bf16_to_f((unsigned short)nl[1]);
        nq[r].z = (acc2[2][r] - mu) * rs * gq.z + bq.z + bf16_to_f((unsigned short)nh[2]) + bf16_to_f((unsigned short)nl[2]);
        nq[r].w = (acc2[3][r] - mu) * rs * gq.w + bq.w + bf16_to_f((unsigned short)nh[3]) + bf16_to_f((unsigned short)nl[3]);
        const int grow = row0 + rl;
        if (!wfDec && grow < N)       // final layer: n never read again -> skip store
            *reinterpret_cast<float4*>(n + (long long)grow * 64 + c4) = nq[r];
    }

    if (wfB) {   // fused u/v (bf16) for next layer
        __builtin_amdgcn_wave_barrier();
        repack1(An, nq, wm, g, c4);    // An residual consumed -> overlay hi plane with n_new
        __builtin_amdgcn_wave_barrier();
        #pragma unroll
        for (int t = 0; t < 4; ++t) acc2[t] = z4;
        gemm64h(An, wfB, rowA, g, lane, acc2);
        #pragma unroll
        for (int r = 0; r < 4; ++r) {
            const int grow = row0 + wm * 16 + g * 4 + r;
            if (grow < N) {
                short4v o;
                o[0] = (short)bf16_rne(acc2[0][r]);
                o[1] = (short)bf16_rne(acc2[1][r]);
                o[2] = (short)bf16_rne(acc2[2][r]);
                o[3] = (short)bf16_rne(acc2[3][r]);
                *reinterpret_cast<short4v*>(u + (long long)grow * 64 + c4) = o;
            }
        }
        #pragma unroll
        for (int t = 0; t < 4; ++t) acc2[t] = z4;
        gemm64h(An, wfC, rowA, g, lane, acc2);
        #pragma unroll
        for (int r = 0; r < 4; ++r) {
            const int grow = row0 + wm * 16 + g * 4 + r;
            if (grow < N) {
                short4v o;
                o[0] = (short)bf16_rne(acc2[0][r]);
                o[1] = (short)bf16_rne(acc2[1][r]);
                o[2] = (short)bf16_rne(acc2[2][r]);
                o[3] = (short)bf16_rne(acc2[3][r]);
                *reinterpret_cast<short4v*>(v + (long long)grow * 64 + c4) = o;
            }
        }
    }

    if (wfDec) {   // fused decoder (layer 3): out = lrelu(n@decW1+db1) @ decW2 + db2
        __builtin_amdgcn_wave_barrier();
        repackW(An, nq, wm, g, c4);    // exact hi/lo overlay with final n
        __builtin_amdgcn_wave_barrier();
        f32x4 acc3[4];
        #pragma unroll
        for (int t = 0; t < 4; ++t) acc3[t] = z4;
        gemm64(An, wfDec, rowA, g, lane, acc3);
        const float4 db1q = *reinterpret_cast<const float4*>(db1 + c4);
        const float db1a[4] = {db1q.x, db1q.y, db1q.z, db1q.w};
        #pragma unroll
        for (int t = 0; t < 4; ++t)
            #pragma unroll
            for (int r = 0; r < 4; ++r) acc3[t][r] = lrelu(acc3[t][r] + db1a[t]);
        const float4 w0 = *reinterpret_cast<const float4*>(dW2 + c4 * 3);
        const float4 w1 = *reinterpret_cast<const float4*>(dW2 + c4 * 3 + 4);
        const float4 w2 = *reinterpret_cast<const float4*>(dW2 + c4 * 3 + 8);
        const float wv[12] = {w0.x,w0.y,w0.z,w0.w, w1.x,w1.y,w1.z,w1.w, w2.x,w2.y,w2.z,w2.w};
        float po[4][3];
        #pragma unroll
        for (int r = 0; r < 4; ++r)
            #pragma unroll
            for (int o = 0; o < 3; ++o)
                po[r][o] = acc3[0][r]*wv[o] + acc3[1][r]*wv[3+o] + acc3[2][r]*wv[6+o] + acc3[3][r]*wv[9+o];
        #pragma unroll
        for (int m = 1; m <= 8; m <<= 1)
            #pragma unroll
            for (int r = 0; r < 4; ++r)
                #pragma unroll
                for (int o = 0; o < 3; ++o)
                    po[r][o] += __shfl_xor(po[r][o], m);
        if (c < 3) {
            #pragma unroll
            for (int r = 0; r < 4; ++r) {
                const int grow = row0 + wm * 16 + g * 4 + r;
                const float val = (c == 0) ? po[r][0] : (c == 1) ? po[r][1] : po[r][2];
                if (grow < N) out[(long long)grow * 3 + c] = db2[c] + val;
            }
        }
    }
}

// ================= CSR build =================
__global__ void k_hist(const int* __restrict__ eidx, int* __restrict__ cnt, int E)
{
    int i = blockIdx.x * 256 + threadIdx.x;
    if (i < E) atomicAdd(&cnt[eidx[2 * i]], 1);
}

__global__ void k_scan1(const int* __restrict__ cnt, int* __restrict__ starts,
                        int* __restrict__ bsum, int n)
{
    __shared__ int sh[256];
    const int tid = threadIdx.x;
    const int i = blockIdx.x * 256 + tid;
    const int val = (i < n) ? cnt[i] : 0;
    sh[tid] = val; __syncthreads();
    for (int off = 1; off < 256; off <<= 1) {
        int t = (tid >= off) ? sh[tid - off] : 0;
        __syncthreads();
        sh[tid] += t;
        __syncthreads();
    }
    if (i < n) starts[i] = sh[tid] - val;
    if (tid == 255) bsum[blockIdx.x] = sh[255];
}

__global__ void k_scan2(int* __restrict__ bsum, int nb)
{
    __shared__ int sh[256];
    const int tid = threadIdx.x;
    const int val = (tid < nb) ? bsum[tid] : 0;
    sh[tid] = val; __syncthreads();
    for (int off = 1; off < 256; off <<= 1) {
        int t = (tid >= off) ? sh[tid - off] : 0;
        __syncthreads();
        sh[tid] += t;
        __syncthreads();
    }
    if (tid < nb) bsum[tid] = sh[tid] - val;
}

__global__ void k_scan3(int* __restrict__ starts, const int* __restrict__ bsum, int n)
{
    int i = blockIdx.x * 256 + threadIdx.x;
    if (i < n) starts[i] += bsum[blockIdx.x];
}

__global__ void k_scatter(const int* __restrict__ eidx, const int* __restrict__ starts,
                          int* __restrict__ cursor, int* __restrict__ csr,
                          int* __restrict__ sp, int* __restrict__ rp, int E)
{
    int i = blockIdx.x * 256 + threadIdx.x;
    if (i < E) {
        const int s = eidx[2 * i];
        const int p = atomicAdd(&cursor[s], 1);
        const int q = starts[s] + p;
        csr[q] = i;
        sp[q] = s;
        rp[q] = eidx[2 * i + 1];
    }
}

extern "C" void kernel_launch(void* const* d_in, const int* in_sizes, int n_in,
                              void* d_out, int out_size, void* d_ws, size_t ws_size,
                              hipStream_t stream)
{
    (void)in_sizes; (void)n_in; (void)out_size; (void)ws_size;
    constexpr int N = 50000, E = 300000, L = 3;

    const float* nodes = (const float*)d_in[0];
    const float* edges = (const float*)d_in[1];
    const int*   eidx  = (const int*)d_in[2];
    const float* neW1 = (const float*)d_in[3];
    const float* neb1 = (const float*)d_in[4];
    const float* neW2 = (const float*)d_in[5];
    const float* neb2 = (const float*)d_in[6];
    const float* neg  = (const float*)d_in[7];
    const float* nebe = (const float*)d_in[8];
    const float* eeW1 = (const float*)d_in[9];
    const float* eeb1 = (const float*)d_in[10];
    const float* eeW2 = (const float*)d_in[11];
    const float* eeb2 = (const float*)d_in[12];
    const float* eeg  = (const float*)d_in[13];
    const float* eebe = (const float*)d_in[14];
    const float* nmW1 = (const float*)d_in[15];
    const float* nmb1 = (const float*)d_in[16];
    const float* nmW2 = (const float*)d_in[17];
    const float* nmb2 = (const float*)d_in[18];
    const float* nmg  = (const float*)d_in[19];
    const float* nmbe = (const float*)d_in[20];
    const float* emW1 = (const float*)d_in[21];
    const float* emb1 = (const float*)d_in[22];
    const float* emW2 = (const float*)d_in[23];
    const float* emb2 = (const float*)d_in[24];
    const float* emg  = (const float*)d_in[25];
    const float* embe = (const float*)d_in[26];
    const float* decW1 = (const float*)d_in[27];
    const float* decb1 = (const float*)d_in[28];
    const float* decW2 = (const float*)d_in[29];
    const float* decb2 = (const float*)d_in[30];

    // workspace: n(f32) | aggr(f32) | ubf | vbf | ints | wf | ebf
    float* n    = (float*)d_ws;                       // N*64 f32
    float* aggr = n + (size_t)N * 64;                 // N*64 f32
    unsigned short* ubf = (unsigned short*)(aggr + (size_t)N * 64);  // N*64 bf16
    unsigned short* vbf = ubf + (size_t)N * 64;       // N*64 bf16
    int* cnt    = (int*)(vbf + (size_t)N * 64);       // N
    int* starts = cnt + N;                            // N
    int* csr    = starts + N;                         // E
    int* bsum   = csr + E;                            // 256
    int* cursor = bsum + 256;                         // N
    int* sp     = cursor + N;                         // E
    int* rp     = sp + E;                             // E
    short* wf   = (short*)(rp + E);                   // 24 * 8192 shorts
    unsigned short* ebf = (unsigned short*)(wf + (size_t)24 * 8192);  // E*64 bf16

    const int nbN = (N + 255) / 256;
    const int nbE = (E + 255) / 256;
    const int nbN64 = (N + 63) / 64;            // 782
    const int nbE64 = (E + 63) / 64;            // 4688 (divisible by 8 -> bijective swizzle)

    const short* wfEE  = wf + (size_t)21 * 8192;
    const short* wfNE  = wf + (size_t)22 * 8192;
    const short* wfDec = wf + (size_t)23 * 8192;

    // ---- weight fragment prep + CSR build ----
    k_prepw<<<24, 256, 0, stream>>>(emW1, emW2, nmW1, nmW2, eeW2, neW2, decW1, wf);
    hipMemsetAsync(cnt, 0, (size_t)N * sizeof(int), stream);
    hipMemsetAsync(cursor, 0, (size_t)N * sizeof(int), stream);
    k_hist<<<nbE, 256, 0, stream>>>(eidx, cnt, E);
    k_scan1<<<nbN, 256, 0, stream>>>(cnt, starts, bsum, N);
    k_scan2<<<1, 256, 0, stream>>>(bsum, nbN);
    k_scan3<<<nbN, 256, 0, stream>>>(starts, bsum, N);
    k_scatter<<<nbE, 256, 0, stream>>>(eidx, starts, cursor, csr, sp, rp, E);

    // ---- encode (node encoder also emits u,v for layer 0; edge encoder writes bf16 e) ----
    const short* wl0 = wf;
    k_enc_mf<16, false, true, false><<<nbN64, 256, 0, stream>>>(
        nodes, nullptr, neW1, neb1, wfNE, neb2, neg, nebe, n,
        wl0 + 8192, wl0 + 2 * 8192, ubf, vbf, N);
    k_enc_mf<8, true, false, true><<<nbE64, 256, 0, stream>>>(
        edges, csr, eeW1, eeb1, wfEE, eeb2, eeg, eebe, (float*)ebf,
        nullptr, nullptr, nullptr, nullptr, E);

    // ---- message-passing layers (layer 3 fuses the decoder; no separate k_dec) ----
    for (int i = 0; i < L; ++i) {
        const short* wl = wf + (size_t)i * 7 * 8192;
        k_edge_mf<<<nbE64, 256, 0, stream>>>(ebf, sp, rp, ubf, vbf, wl, wl + 3 * 8192,
                                             emb1 + i * 64, emb2 + i * 64,
                                             emg + i * 64, embe + i * 64, E);
        k_aggr<<<(N + 3) / 4, 256, 0, stream>>>(ebf, starts, cnt, aggr, N);
        const bool last = (i + 1 == L);
        const short* wln = last ? nullptr : wf + (size_t)(i + 1) * 7 * 8192;
        k_node_mf<<<nbN64, 256, 0, stream>>>(n, aggr,
                                             wl + 4 * 8192, wl + 5 * 8192, wl + 6 * 8192,
                                             nmb1 + i * 64, nmb2 + i * 64,
                                             nmg + i * 64, nmbe + i * 64,
                                             wln ? wln + 8192 : nullptr,
                                             wln ? wln + 2 * 8192 : nullptr,
                                             ubf, vbf,
                                             last ? wfDec : nullptr,
                                             decb1, decW2, decb2,
                                             (float*)d_out, N);
    }
}